// Round 10
// baseline (871.084 us; speedup 1.0000x reference)
//
#include <hip/hip_runtime.h>

// SparseBasicBlock: conv1(gather-GEMM) -> BN+ReLU -> conv2 -> BN -> +residual -> ReLU
// bf16 MFMA 16x16x32, fp32 accum. Conv: MTILE=64, 512 threads (8 waves = 2 row
// groups x 4 col groups), 3 x 16KB LDS gather pipeline (2-deep) via
// global_load_lds (pre-swizzled source, linear LDS dest), register-double-
// buffered B, uniform counted vmcnt(10) + one raw s_barrier per ko.

#define C_CH 128
#define K_OFF 9
#define MTILE 64

typedef __attribute__((ext_vector_type(8))) short bf16x8;
typedef __attribute__((ext_vector_type(4))) float f32x4;
typedef __attribute__((ext_vector_type(8))) unsigned short u16x8;

typedef __attribute__((address_space(1))) const unsigned int* gas_p;
typedef __attribute__((address_space(3))) unsigned int* las_p;

__device__ __forceinline__ void gload_lds16(const unsigned short* g, unsigned short* l) {
    __builtin_amdgcn_global_load_lds((gas_p)g, (las_p)l, 16, 0, 0);
}

__device__ __forceinline__ unsigned short f2b(float f) {
    union { float f; unsigned u; } v; v.f = f;
    unsigned r = v.u + 0x7fffu + ((v.u >> 16) & 1u);   // round-to-nearest-even
    return (unsigned short)(r >> 16);
}
__device__ __forceinline__ float b2f(unsigned short h) {
    union { unsigned u; float f; } v; v.u = ((unsigned)h) << 16;
    return v.f;
}

// ---------------- pre-kernels ----------------

// block 0: zero stats + flags + two zero-sentinel rows; blocks 1..64: detect mask dtype
__global__ void init_detect_k(float* stats, unsigned int* zrow1, unsigned int* zrow2,
                              const unsigned char* __restrict__ m, int* flagA, int* flagB) {
    int t = threadIdx.x;
    if (blockIdx.x == 0) {
        if (t < 256) { stats[t] = 0.f; stats[256 + t] = 0.f; }
        if (t >= 256 && t < 258) ((int*)stats)[1024 + (t - 256)] = 0;  // flagA, flagB
        if (t < 64) { zrow1[t] = 0u; zrow2[t] = 0u; }
    } else {
        int i = (blockIdx.x - 1) * 256 + t;   // first 16KB of mask
        unsigned char v = m[i];
        if ((i & 3) != 0 && v != 0) atomicOr(flagA, 1);
        if (v > 1) atomicOr(flagB, 1);
    }
}

// merged: convert feat->bf16 | pack W1,W2 (16x16 B-fragment layout)
// Wp[((ko*8+nt)*4+ks)*512 + lane*8 + j] = W[ko][ks*32+(lane>>4)*8+j][nt*16+(lane&15)]
__global__ void prep_k(const float* __restrict__ x, unsigned short* __restrict__ y, int n4,
                       const float* __restrict__ W1, unsigned short* __restrict__ Wp1,
                       const float* __restrict__ W2, unsigned short* __restrict__ Wp2) {
    const int PACK = K_OFF * 8 * 4 * 512;      // per-tensor packed elements
    int i = blockIdx.x * blockDim.x + threadIdx.x;
    int s = gridDim.x * blockDim.x;
    int tot = n4 + 2 * PACK;
    for (; i < tot; i += s) {
        if (i < n4) {
            float4 f = ((const float4*)x)[i];
            ushort4 o;
            o.x = f2b(f.x); o.y = f2b(f.y); o.z = f2b(f.z); o.w = f2b(f.w);
            ((ushort4*)y)[i] = o;
        } else {
            int ii = i - n4;
            const float* W = (ii < PACK) ? W1 : W2;
            unsigned short* Wp = (ii < PACK) ? Wp1 : Wp2;
            if (ii >= PACK) ii -= PACK;
            int j = ii & 7;
            int l = (ii >> 3) & 63;
            int frag = ii >> 9;
            int ks = frag & 3;
            int nt = (frag >> 2) & 7;
            int ko = frag >> 5;
            int cin = ks * 32 + (l >> 4) * 8 + j;
            int cout = nt * 16 + (l & 15);
            Wp[ii] = f2b(W[ko * C_CH * C_CH + cin * C_CH + cout]);
        }
    }
}

// ---------------- gather-GEMM conv ----------------

__global__ __launch_bounds__(512, 2) void conv_kernel(
    const unsigned short* __restrict__ Xb,   // (N+1) x 128 bf16 (row N = zeros)
    const unsigned short* __restrict__ Wp,   // packed weights (fragment layout)
    const int* __restrict__ nidx,            // N x 9 rulebook indices
    const void* __restrict__ nmask,          // N x 9 mask (dtype per flags)
    const int* __restrict__ flagA, const int* __restrict__ flagB,
    int Nzero,                               // zero-sentinel row index (= N)
    unsigned short* __restrict__ Yraw,       // N x 128 bf16 raw conv output
    float* __restrict__ statS, float* __restrict__ statQ)
{
    const int tid = threadIdx.x;
    const int lane = tid & 63;
    const int wv = tid >> 6;          // 0..7
    const int wr = wv >> 2;           // row group 0..1 (32 rows each)
    const int wc = wv & 3;            // col group 0..3 (32 cols each)
    const int tile = blockIdx.x * MTILE;
    const int asub = lane >> 4;       // 0..3
    const int l15 = lane & 15;

    __shared__ alignas(16) unsigned short At[3][MTILE * C_CH]; // 3 x 16KB, linear
    __shared__ int sIdxT[K_OFF][MTILE];                        // 2.25KB

    // fold mask + idx inline
    {
        int fa = *flagA, fb = *flagB;
        for (int i = tid; i < MTILE * K_OFF; i += 512) {
            int r = i / K_OFF, k = i - r * K_OFF;
            size_t gi = (size_t)(tile + r) * K_OFF + k;
            bool t;
            if (!fa)       t = ((const int*)nmask)[gi] != 0;            // int32
            else if (fb)   t = ((const unsigned*)nmask)[gi] != 0;       // float32 bit test
            else           t = ((const unsigned char*)nmask)[gi] != 0;  // uint8 bool
            sIdxT[k][r] = t ? nidx[gi] : Nzero;
        }
    }
    __syncthreads();

    const int r_st = tid >> 4;      // 0..31
    const int ch_st = tid & 15;     // 0..15

    // STAGE(buf, ko): 2 async global->LDS 16B loads per thread; LDS dest is
    // wave-uniform base + lane*16 (gload_lds requirement; verified: r_st
    // decomposes so dest == wavebase + lane*16); global source pre-XOR-swizzled
    // so the swizzled ds_read below recovers the right chunk.
    #define STAGE(buf, ko)                                                        \
        {                                                                         \
            _Pragma("unroll")                                                     \
            for (int jr = 0; jr < 2; ++jr) {                                      \
                int r = jr * 32 + r_st;                                           \
                int g = sIdxT[ko][r];                                             \
                const unsigned short* src =                                       \
                    Xb + (size_t)g * C_CH + ((ch_st ^ (r & 7)) * 8);              \
                unsigned short* dst = &At[buf][r * C_CH + ch_st * 8];             \
                gload_lds16(src, dst);                                            \
            }                                                                     \
        }

    // LOADB*(ko): 8 x 16B global loads of this wave's 2 col-tiles into named regs
    #define LOADB0(ko)                                                            \
        {                                                                         \
            const unsigned short* wb = Wp + (size_t)(ko) * (8 * 4 * 512) + lane * 8; \
            _Pragma("unroll")                                                     \
            for (int ks = 0; ks < 4; ++ks) {                                      \
                b0a[ks] = *(const bf16x8*)(wb + ((wc * 2 + 0) * 4 + ks) * 512);   \
                b0b[ks] = *(const bf16x8*)(wb + ((wc * 2 + 1) * 4 + ks) * 512);   \
            }                                                                     \
        }
    #define LOADB1(ko)                                                            \
        {                                                                         \
            const unsigned short* wb = Wp + (size_t)(ko) * (8 * 4 * 512) + lane * 8; \
            _Pragma("unroll")                                                     \
            for (int ks = 0; ks < 4; ++ks) {                                      \
                b1a[ks] = *(const bf16x8*)(wb + ((wc * 2 + 0) * 4 + ks) * 512);   \
                b1b[ks] = *(const bf16x8*)(wb + ((wc * 2 + 1) * 4 + ks) * 512);   \
            }                                                                     \
        }

    f32x4 acc[2][2];
    #pragma unroll
    for (int m = 0; m < 2; ++m) { acc[m][0] = (f32x4){0,0,0,0}; acc[m][1] = (f32x4){0,0,0,0}; }

    bf16x8 b0a[4], b0b[4], b1a[4], b1b[4];

    // prologue queue: s0(2) B0(8) s1(2)
    STAGE(0, 0);
    LOADB0(0);
    STAGE(1, 1);

    // Per iteration KO (fully unrolled):
    //   [LOADB(KO+1) -> other parity] [sched_barrier]
    //   [s_waitcnt vmcnt(VM)] [s_barrier] [sched_barrier]
    //   [STAGE(KO+2) -> buf (KO+2)%3]  (last read at iter KO-1, safe)
    //   [setprio(1): 8x ds_read A from buf KO%3 + 16 MFMA]
    // Queue at the wait: s(KO)2 B(KO)8 | s(KO+1)2 B(KO+1)8 -> vmcnt(10) exact.
    #define CONV_ITER(KO, BA, BB, LB, VM)                                         \
        {                                                                         \
            if ((KO) + 1 < K_OFF) { LB((KO) + 1); }                               \
            __builtin_amdgcn_sched_barrier(0);                                    \
            asm volatile("s_waitcnt vmcnt(" #VM ")" ::: "memory");                \
            __builtin_amdgcn_s_barrier();                                         \
            __builtin_amdgcn_sched_barrier(0);                                    \
            if ((KO) + 2 < K_OFF) { STAGE(((KO) + 2) % 3, (KO) + 2); }            \
            __builtin_amdgcn_s_setprio(1);                                        \
            _Pragma("unroll")                                                     \
            for (int m = 0; m < 2; ++m) {                                         \
                bf16x8 a[4];                                                      \
                _Pragma("unroll")                                                 \
                for (int ks = 0; ks < 4; ++ks) {                                  \
                    int row = wr * 32 + m * 16 + l15;                             \
                    int sc = (ks * 4 + asub) ^ (row & 7);                         \
                    a[ks] = *(const bf16x8*)((const char*)At[(KO) % 3] + row * 256 + sc * 16); \
                }                                                                 \
                _Pragma("unroll")                                                 \
                for (int ks = 0; ks < 4; ++ks) {                                  \
                    acc[m][0] = __builtin_amdgcn_mfma_f32_16x16x32_bf16(a[ks], BA[ks], acc[m][0], 0, 0, 0); \
                    acc[m][1] = __builtin_amdgcn_mfma_f32_16x16x32_bf16(a[ks], BB[ks], acc[m][1], 0, 0, 0); \
                }                                                                 \
            }                                                                     \
            __builtin_amdgcn_s_setprio(0);                                        \
        }

    CONV_ITER(0, b0a, b0b, LOADB1, 10)
    CONV_ITER(1, b1a, b1b, LOADB0, 10)
    CONV_ITER(2, b0a, b0b, LOADB1, 10)
    CONV_ITER(3, b1a, b1b, LOADB0, 10)
    CONV_ITER(4, b0a, b0b, LOADB1, 10)
    CONV_ITER(5, b1a, b1b, LOADB0, 10)
    CONV_ITER(6, b0a, b0b, LOADB1, 10)
    CONV_ITER(7, b1a, b1b, LOADB0, 10)
    CONV_ITER(8, b0a, b0b, LOADB1, 0)
    #undef CONV_ITER
    #undef STAGE
    #undef LOADB0
    #undef LOADB1

    // ---- per-channel stats (wave owns cols [(wc*2+j)*16 .. +16), both wr add) ----
    #pragma unroll
    for (int j = 0; j < 2; ++j) {
        float s = 0.f, q = 0.f;
        #pragma unroll
        for (int m = 0; m < 2; ++m)
            #pragma unroll
            for (int r = 0; r < 4; ++r) { float v = acc[m][j][r]; s += v; q += v * v; }
        s += __shfl_xor(s, 16); s += __shfl_xor(s, 32);
        q += __shfl_xor(q, 16); q += __shfl_xor(q, 32);
        if (lane < 16) {
            atomicAdd(&statS[(wc * 2 + j) * 16 + lane], s);
            atomicAdd(&statQ[(wc * 2 + j) * 16 + lane], q);
        }
    }

    // ---- write raw conv output (bf16) ----
    #pragma unroll
    for (int m = 0; m < 2; ++m)
        #pragma unroll
        for (int j = 0; j < 2; ++j) {
            int col = (wc * 2 + j) * 16 + l15;
            #pragma unroll
            for (int r = 0; r < 4; ++r) {
                int row = tile + wr * 32 + m * 16 + asub * 4 + r;
                Yraw[(size_t)row * C_CH + col] = f2b(acc[m][j][r]);
            }
        }
}

// ---------------- BN finalize / apply ----------------

__global__ void finalize_bn_k(const float* __restrict__ S, const float* __restrict__ Q,
                              const float* __restrict__ gamma, const float* __restrict__ beta,
                              float* __restrict__ scale, float* __restrict__ bias, float invN) {
    int c = threadIdx.x;
    if (c < C_CH) {
        float mu = S[c] * invN;
        float var = Q[c] * invN - mu * mu;
        float inv = rsqrtf(var + 1e-4f);
        float sc = gamma[c] * inv;
        scale[c] = sc;
        bias[c] = beta[c] - mu * sc;
    }
}

__global__ void bn_relu_k(unsigned short* __restrict__ y,
                          const float* __restrict__ scale, const float* __restrict__ bias, int n8) {
    int i0 = blockIdx.x * blockDim.x + threadIdx.x;
    int S = gridDim.x * blockDim.x;
    int c0 = (i0 * 8) & (C_CH - 1);
    float sc[8], bs[8];
    #pragma unroll
    for (int j = 0; j < 8; ++j) { sc[j] = scale[c0 + j]; bs[j] = bias[c0 + j]; }
    for (int i = i0; i < n8; i += S) {
        u16x8 v = ((const u16x8*)y)[i];
        #pragma unroll
        for (int j = 0; j < 8; ++j) {
            float x = b2f((unsigned short)v[j]);
            x = fmaxf(x * sc[j] + bs[j], 0.f);
            v[j] = (short)f2b(x);
        }
        ((u16x8*)y)[i] = v;
    }
}

__global__ void final_fuse_k(const unsigned short* __restrict__ raw,
                             const float* __restrict__ feat,
                             const float* __restrict__ scale, const float* __restrict__ bias,
                             float* __restrict__ out, int n4) {
    int i0 = blockIdx.x * blockDim.x + threadIdx.x;
    int S = gridDim.x * blockDim.x;
    int c0 = (i0 * 4) & (C_CH - 1);
    float sc[4], bs[4];
    #pragma unroll
    for (int j = 0; j < 4; ++j) { sc[j] = scale[c0 + j]; bs[j] = bias[c0 + j]; }
    for (int i = i0; i < n4; i += S) {
        ushort4 r = ((const ushort4*)raw)[i];
        float4 f = ((const float4*)feat)[i];
        float4 o;
        o.x = fmaxf(b2f(r.x) * sc[0] + bs[0] + f.x, 0.f);
        o.y = fmaxf(b2f(r.y) * sc[1] + bs[1] + f.y, 0.f);
        o.z = fmaxf(b2f(r.z) * sc[2] + bs[2] + f.z, 0.f);
        o.w = fmaxf(b2f(r.w) * sc[3] + bs[3] + f.w, 0.f);
        ((float4*)out)[i] = o;
    }
}

// ---------------- launch ----------------

extern "C" void kernel_launch(void* const* d_in, const int* in_sizes, int n_in,
                              void* d_out, int out_size, void* d_ws, size_t ws_size,
                              hipStream_t stream) {
    const float* feat = (const float*)d_in[0];
    const float* W1 = (const float*)d_in[1];
    const float* W2 = (const float*)d_in[2];
    const float* g1 = (const float*)d_in[3];
    const float* b1 = (const float*)d_in[4];
    const float* g2 = (const float*)d_in[5];
    const float* b2 = (const float*)d_in[6];
    const int* nidx = (const int*)d_in[7];
    const void* nmask = d_in[8];

    const int N = in_sizes[0] / C_CH;   // 400000

    char* ws = (char*)d_ws;
    unsigned short* featb = (unsigned short*)ws;                          // (N+1) x 128 bf16
    size_t off = (size_t)(N + 1) * C_CH * 2;
    off = (off + 255) & ~(size_t)255;
    unsigned short* Wp1 = (unsigned short*)(ws + off); off += (size_t)K_OFF * C_CH * C_CH * 2;
    unsigned short* Wp2 = (unsigned short*)(ws + off); off += (size_t)K_OFF * C_CH * C_CH * 2;
    float* stats = (float*)(ws + off);
    float* S1 = stats;        float* Q1 = stats + 128;
    float* S2 = stats + 256;  float* Q2 = stats + 384;
    float* sc1 = stats + 512; float* bi1 = stats + 640;
    float* sc2 = stats + 768; float* bi2 = stats + 896;
    int* flagA = ((int*)stats) + 1024;
    int* flagB = ((int*)stats) + 1025;

    // scratch inside d_out: y1 = rows [0, N] bf16 (~102.4MB); rewritten by final_fuse.
    unsigned short* y1 = (unsigned short*)d_out;
    unsigned short* out2raw = featb;               // reuse feat-bf16 region after conv1

    hipLaunchKernelGGL(init_detect_k, dim3(65), dim3(256), 0, stream,
                       stats, (unsigned int*)(featb + (size_t)N * C_CH),
                       (unsigned int*)(y1 + (size_t)N * C_CH),
                       (const unsigned char*)nmask, flagA, flagB);
    hipLaunchKernelGGL(prep_k, dim3(2048), dim3(256), 0, stream,
                       feat, featb, N * C_CH / 4,
                       W1, Wp1, W2, Wp2);

    hipLaunchKernelGGL(conv_kernel, dim3(N / MTILE), dim3(512), 0, stream,
                       featb, Wp1, nidx, nmask, flagA, flagB, N, y1, S1, Q1);
    hipLaunchKernelGGL(finalize_bn_k, dim3(1), dim3(128), 0, stream, S1, Q1, g1, b1, sc1, bi1, 1.0f / N);
    hipLaunchKernelGGL(bn_relu_k, dim3(2048), dim3(256), 0, stream, y1, sc1, bi1, N * C_CH / 8);

    hipLaunchKernelGGL(conv_kernel, dim3(N / MTILE), dim3(512), 0, stream,
                       y1, Wp2, nidx, nmask, flagA, flagB, N, out2raw, S2, Q2);
    hipLaunchKernelGGL(finalize_bn_k, dim3(1), dim3(128), 0, stream, S2, Q2, g2, b2, sc2, bi2, 1.0f / N);
    hipLaunchKernelGGL(final_fuse_k, dim3(2048), dim3(256), 0, stream,
                       out2raw, feat, sc2, bi2, (float*)d_out, N * C_CH / 4);
}

// Round 11
// 554.908 us; speedup vs baseline: 1.5698x; 1.5698x over previous
//
#include <hip/hip_runtime.h>

// SparseBasicBlock: conv1(gather-GEMM) -> BN+ReLU -> conv2 -> BN -> +residual -> ReLU
// bf16 MFMA 16x16x32, fp32 accum. Conv: MTILE=64, 4 waves (col-split), 3-buffer
// LDS gather pipeline (2-deep) via global_load_lds + register-double-buffered
// B-fragments, uniform counted vmcnt(12) + one raw s_barrier per ko.
// Mask folded inline in the conv (no eidx pass).

#define C_CH 128
#define K_OFF 9
#define MTILE 64

typedef __attribute__((ext_vector_type(8))) short bf16x8;
typedef __attribute__((ext_vector_type(4))) float f32x4;
typedef __attribute__((ext_vector_type(8))) unsigned short u16x8;

typedef __attribute__((address_space(1))) const unsigned int* gas_p;
typedef __attribute__((address_space(3))) unsigned int* las_p;

__device__ __forceinline__ void gload_lds16(const unsigned short* g, unsigned short* l) {
    __builtin_amdgcn_global_load_lds((gas_p)g, (las_p)l, 16, 0, 0);
}

__device__ __forceinline__ unsigned short f2b(float f) {
    union { float f; unsigned u; } v; v.f = f;
    unsigned r = v.u + 0x7fffu + ((v.u >> 16) & 1u);   // round-to-nearest-even
    return (unsigned short)(r >> 16);
}
__device__ __forceinline__ float b2f(unsigned short h) {
    union { unsigned u; float f; } v; v.u = ((unsigned)h) << 16;
    return v.f;
}

// ---------------- pre-kernels ----------------

// block 0: zero stats + flags + two zero-sentinel rows; blocks 1..64: detect mask dtype
__global__ void init_detect_k(float* stats, unsigned int* zrow1, unsigned int* zrow2,
                              const unsigned char* __restrict__ m, int* flagA, int* flagB) {
    int t = threadIdx.x;
    if (blockIdx.x == 0) {
        if (t < 256) { stats[t] = 0.f; stats[256 + t] = 0.f; }
        if (t >= 256 && t < 258) ((int*)stats)[1024 + (t - 256)] = 0;  // flagA, flagB
        if (t < 64) { zrow1[t] = 0u; zrow2[t] = 0u; }
    } else {
        int i = (blockIdx.x - 1) * 256 + t;   // first 16KB of mask
        unsigned char v = m[i];
        if ((i & 3) != 0 && v != 0) atomicOr(flagA, 1);
        if (v > 1) atomicOr(flagB, 1);
    }
}

// merged: convert feat->bf16 | pack W1,W2 (16x16 B-fragment layout)
// Wp[((ko*8+nt)*4+ks)*512 + lane*8 + j] = W[ko][ks*32+(lane>>4)*8+j][nt*16+(lane&15)]
__global__ void prep_k(const float* __restrict__ x, unsigned short* __restrict__ y, int n4,
                       const float* __restrict__ W1, unsigned short* __restrict__ Wp1,
                       const float* __restrict__ W2, unsigned short* __restrict__ Wp2) {
    const int PACK = K_OFF * 8 * 4 * 512;      // per-tensor packed elements
    int i = blockIdx.x * blockDim.x + threadIdx.x;
    int s = gridDim.x * blockDim.x;
    int tot = n4 + 2 * PACK;
    for (; i < tot; i += s) {
        if (i < n4) {
            float4 f = ((const float4*)x)[i];
            ushort4 o;
            o.x = f2b(f.x); o.y = f2b(f.y); o.z = f2b(f.z); o.w = f2b(f.w);
            ((ushort4*)y)[i] = o;
        } else {
            int ii = i - n4;
            const float* W = (ii < PACK) ? W1 : W2;
            unsigned short* Wp = (ii < PACK) ? Wp1 : Wp2;
            if (ii >= PACK) ii -= PACK;
            int j = ii & 7;
            int l = (ii >> 3) & 63;
            int frag = ii >> 9;
            int ks = frag & 3;
            int nt = (frag >> 2) & 7;
            int ko = frag >> 5;
            int cin = ks * 32 + (l >> 4) * 8 + j;
            int cout = nt * 16 + (l & 15);
            Wp[ii] = f2b(W[ko * C_CH * C_CH + cin * C_CH + cout]);
        }
    }
}

// ---------------- gather-GEMM conv ----------------

__global__ __launch_bounds__(256, 3) void conv_kernel(
    const unsigned short* __restrict__ Xb,   // (N+1) x 128 bf16 (row N = zeros)
    const unsigned short* __restrict__ Wp,   // packed weights (fragment layout)
    const int* __restrict__ nidx,            // N x 9 rulebook indices
    const void* __restrict__ nmask,          // N x 9 mask (dtype per flags)
    const int* __restrict__ flagA, const int* __restrict__ flagB,
    int Nzero,                               // zero-sentinel row index (= N)
    unsigned short* __restrict__ Yraw,       // N x 128 bf16 raw conv output
    float* __restrict__ statS, float* __restrict__ statQ)
{
    const int tid = threadIdx.x;
    const int lane = tid & 63;
    const int wv = tid >> 6;          // wave 0..3 owns cols [wv*32, wv*32+32)
    const int tile = blockIdx.x * MTILE;
    const int asub = lane >> 4;       // 0..3
    const int l15 = lane & 15;

    __shared__ alignas(16) unsigned short At[3][MTILE * C_CH]; // 3 x 16KB, linear
    __shared__ int sIdxT[K_OFF][MTILE];                        // 2.25KB

    // fold mask + idx inline (no separate eidx pass)
    {
        int fa = *flagA, fb = *flagB;
        for (int i = tid; i < MTILE * K_OFF; i += 256) {
            int r = i / K_OFF, k = i - r * K_OFF;
            size_t gi = (size_t)(tile + r) * K_OFF + k;
            bool t;
            if (!fa)       t = ((const int*)nmask)[gi] != 0;            // int32
            else if (fb)   t = ((const unsigned*)nmask)[gi] != 0;       // float32 bit test
            else           t = ((const unsigned char*)nmask)[gi] != 0;  // uint8 bool
            sIdxT[k][r] = t ? nidx[gi] : Nzero;
        }
    }
    __syncthreads();

    const int r_st = tid >> 4;      // 0..15
    const int ch_st = tid & 15;     // 0..15

    // STAGE(buf, ko): 4 async global->LDS 16B loads; LDS dest lane-linear
    // (gload_lds requirement); global source pre-XOR-swizzled so the swizzled
    // ds_read below recovers the right chunk.
    #define STAGE(buf, ko)                                                        \
        {                                                                         \
            _Pragma("unroll")                                                     \
            for (int jr = 0; jr < 4; ++jr) {                                      \
                int r = jr * 16 + r_st;                                           \
                int g = sIdxT[ko][r];                                             \
                const unsigned short* src =                                       \
                    Xb + (size_t)g * C_CH + ((ch_st ^ (r & 7)) * 8);              \
                unsigned short* dst = &At[buf][r * C_CH + ch_st * 8];             \
                gload_lds16(src, dst);                                            \
            }                                                                     \
        }

    // LOADB*(ko): 8 x 16B global loads of this wave's 2 col-tiles into named regs
    #define LOADB0(ko)                                                            \
        {                                                                         \
            const unsigned short* wb = Wp + (size_t)(ko) * (8 * 4 * 512) + lane * 8; \
            _Pragma("unroll")                                                     \
            for (int ks = 0; ks < 4; ++ks) {                                      \
                b0a[ks] = *(const bf16x8*)(wb + ((wv * 2 + 0) * 4 + ks) * 512);   \
                b0b[ks] = *(const bf16x8*)(wb + ((wv * 2 + 1) * 4 + ks) * 512);   \
            }                                                                     \
        }
    #define LOADB1(ko)                                                            \
        {                                                                         \
            const unsigned short* wb = Wp + (size_t)(ko) * (8 * 4 * 512) + lane * 8; \
            _Pragma("unroll")                                                     \
            for (int ks = 0; ks < 4; ++ks) {                                      \
                b1a[ks] = *(const bf16x8*)(wb + ((wv * 2 + 0) * 4 + ks) * 512);   \
                b1b[ks] = *(const bf16x8*)(wb + ((wv * 2 + 1) * 4 + ks) * 512);   \
            }                                                                     \
        }

    f32x4 acc[4][2];
    #pragma unroll
    for (int m = 0; m < 4; ++m) { acc[m][0] = (f32x4){0,0,0,0}; acc[m][1] = (f32x4){0,0,0,0}; }

    bf16x8 b0a[4], b0b[4], b1a[4], b1b[4];

    // prologue queue: s0(4) B0(8) s1(4)
    STAGE(0, 0);
    LOADB0(0);
    STAGE(1, 1);

    // Per iteration KO (fully unrolled):
    //   [LOADB(KO+1) -> other parity regs] [sched_barrier]
    //   [s_waitcnt vmcnt(VM)] [s_barrier] [sched_barrier]
    //   [STAGE(KO+2)] [setprio(1): 16x ds_read A + 32 MFMA]
    // Queue at the wait: s(KO) B(KO) | s(KO+1) B(KO+1) -> vmcnt(12) exact.
    #define CONV_ITER(KO, BA, BB, LB, VM)                                         \
        {                                                                         \
            if ((KO) + 1 < K_OFF) { LB((KO) + 1); }                               \
            __builtin_amdgcn_sched_barrier(0);                                    \
            asm volatile("s_waitcnt vmcnt(" #VM ")" ::: "memory");                \
            __builtin_amdgcn_s_barrier();                                         \
            __builtin_amdgcn_sched_barrier(0);                                    \
            if ((KO) + 2 < K_OFF) { STAGE((((KO) + 2) % 3), (KO) + 2); }          \
            __builtin_amdgcn_s_setprio(1);                                        \
            _Pragma("unroll")                                                     \
            for (int m = 0; m < 4; ++m) {                                         \
                bf16x8 a[4];                                                      \
                _Pragma("unroll")                                                 \
                for (int ks = 0; ks < 4; ++ks) {                                  \
                    int row = m * 16 + l15;                                       \
                    int sc = (ks * 4 + asub) ^ (row & 7);                         \
                    a[ks] = *(const bf16x8*)((const char*)At[(KO) % 3] + row * 256 + sc * 16); \
                }                                                                 \
                _Pragma("unroll")                                                 \
                for (int ks = 0; ks < 4; ++ks) {                                  \
                    acc[m][0] = __builtin_amdgcn_mfma_f32_16x16x32_bf16(a[ks], BA[ks], acc[m][0], 0, 0, 0); \
                    acc[m][1] = __builtin_amdgcn_mfma_f32_16x16x32_bf16(a[ks], BB[ks], acc[m][1], 0, 0, 0); \
                }                                                                 \
            }                                                                     \
            __builtin_amdgcn_s_setprio(0);                                        \
        }

    CONV_ITER(0, b0a, b0b, LOADB1, 12)
    CONV_ITER(1, b1a, b1b, LOADB0, 12)
    CONV_ITER(2, b0a, b0b, LOADB1, 12)
    CONV_ITER(3, b1a, b1b, LOADB0, 12)
    CONV_ITER(4, b0a, b0b, LOADB1, 12)
    CONV_ITER(5, b1a, b1b, LOADB0, 12)
    CONV_ITER(6, b0a, b0b, LOADB1, 12)
    CONV_ITER(7, b1a, b1b, LOADB0, 12)
    CONV_ITER(8, b0a, b0b, LOADB1, 0)
    #undef CONV_ITER
    #undef STAGE
    #undef LOADB0
    #undef LOADB1

    // ---- per-channel stats (each wave owns channels [wv*32, wv*32+32)) ----
    #pragma unroll
    for (int j = 0; j < 2; ++j) {
        float s = 0.f, q = 0.f;
        #pragma unroll
        for (int m = 0; m < 4; ++m)
            #pragma unroll
            for (int r = 0; r < 4; ++r) { float v = acc[m][j][r]; s += v; q += v * v; }
        s += __shfl_xor(s, 16); s += __shfl_xor(s, 32);
        q += __shfl_xor(q, 16); q += __shfl_xor(q, 32);
        if (lane < 16) {
            atomicAdd(&statS[wv * 32 + j * 16 + lane], s);
            atomicAdd(&statQ[wv * 32 + j * 16 + lane], q);
        }
    }

    // ---- write raw conv output (bf16) ----
    #pragma unroll
    for (int m = 0; m < 4; ++m)
        #pragma unroll
        for (int j = 0; j < 2; ++j) {
            int col = (wv * 2 + j) * 16 + l15;
            #pragma unroll
            for (int r = 0; r < 4; ++r) {
                int row = tile + m * 16 + asub * 4 + r;
                Yraw[(size_t)row * C_CH + col] = f2b(acc[m][j][r]);
            }
        }
}

// ---------------- BN finalize / apply ----------------

__global__ void finalize_bn_k(const float* __restrict__ S, const float* __restrict__ Q,
                              const float* __restrict__ gamma, const float* __restrict__ beta,
                              float* __restrict__ scale, float* __restrict__ bias, float invN) {
    int c = threadIdx.x;
    if (c < C_CH) {
        float mu = S[c] * invN;
        float var = Q[c] * invN - mu * mu;
        float inv = rsqrtf(var + 1e-4f);
        float sc = gamma[c] * inv;
        scale[c] = sc;
        bias[c] = beta[c] - mu * sc;
    }
}

__global__ void bn_relu_k(unsigned short* __restrict__ y,
                          const float* __restrict__ scale, const float* __restrict__ bias, int n8) {
    int i0 = blockIdx.x * blockDim.x + threadIdx.x;
    int S = gridDim.x * blockDim.x;
    int c0 = (i0 * 8) & (C_CH - 1);
    float sc[8], bs[8];
    #pragma unroll
    for (int j = 0; j < 8; ++j) { sc[j] = scale[c0 + j]; bs[j] = bias[c0 + j]; }
    for (int i = i0; i < n8; i += S) {
        u16x8 v = ((const u16x8*)y)[i];
        #pragma unroll
        for (int j = 0; j < 8; ++j) {
            float x = b2f((unsigned short)v[j]);
            x = fmaxf(x * sc[j] + bs[j], 0.f);
            v[j] = (short)f2b(x);
        }
        ((u16x8*)y)[i] = v;
    }
}

__global__ void final_fuse_k(const unsigned short* __restrict__ raw,
                             const float* __restrict__ feat,
                             const float* __restrict__ scale, const float* __restrict__ bias,
                             float* __restrict__ out, int n4) {
    int i0 = blockIdx.x * blockDim.x + threadIdx.x;
    int S = gridDim.x * blockDim.x;
    int c0 = (i0 * 4) & (C_CH - 1);
    float sc[4], bs[4];
    #pragma unroll
    for (int j = 0; j < 4; ++j) { sc[j] = scale[c0 + j]; bs[j] = bias[c0 + j]; }
    for (int i = i0; i < n4; i += S) {
        ushort4 r = ((const ushort4*)raw)[i];
        float4 f = ((const float4*)feat)[i];
        float4 o;
        o.x = fmaxf(b2f(r.x) * sc[0] + bs[0] + f.x, 0.f);
        o.y = fmaxf(b2f(r.y) * sc[1] + bs[1] + f.y, 0.f);
        o.z = fmaxf(b2f(r.z) * sc[2] + bs[2] + f.z, 0.f);
        o.w = fmaxf(b2f(r.w) * sc[3] + bs[3] + f.w, 0.f);
        ((float4*)out)[i] = o;
    }
}

// ---------------- launch ----------------

extern "C" void kernel_launch(void* const* d_in, const int* in_sizes, int n_in,
                              void* d_out, int out_size, void* d_ws, size_t ws_size,
                              hipStream_t stream) {
    const float* feat = (const float*)d_in[0];
    const float* W1 = (const float*)d_in[1];
    const float* W2 = (const float*)d_in[2];
    const float* g1 = (const float*)d_in[3];
    const float* b1 = (const float*)d_in[4];
    const float* g2 = (const float*)d_in[5];
    const float* b2 = (const float*)d_in[6];
    const int* nidx = (const int*)d_in[7];
    const void* nmask = d_in[8];

    const int N = in_sizes[0] / C_CH;   // 400000

    char* ws = (char*)d_ws;
    unsigned short* featb = (unsigned short*)ws;                          // (N+1) x 128 bf16
    size_t off = (size_t)(N + 1) * C_CH * 2;
    off = (off + 255) & ~(size_t)255;
    unsigned short* Wp1 = (unsigned short*)(ws + off); off += (size_t)K_OFF * C_CH * C_CH * 2;
    unsigned short* Wp2 = (unsigned short*)(ws + off); off += (size_t)K_OFF * C_CH * C_CH * 2;
    float* stats = (float*)(ws + off);
    float* S1 = stats;        float* Q1 = stats + 128;
    float* S2 = stats + 256;  float* Q2 = stats + 384;
    float* sc1 = stats + 512; float* bi1 = stats + 640;
    float* sc2 = stats + 768; float* bi2 = stats + 896;
    int* flagA = ((int*)stats) + 1024;
    int* flagB = ((int*)stats) + 1025;

    // scratch inside d_out: y1 = rows [0, N] bf16 (~102.4MB); rewritten by final_fuse.
    unsigned short* y1 = (unsigned short*)d_out;
    unsigned short* out2raw = featb;               // reuse feat-bf16 region after conv1

    hipLaunchKernelGGL(init_detect_k, dim3(65), dim3(256), 0, stream,
                       stats, (unsigned int*)(featb + (size_t)N * C_CH),
                       (unsigned int*)(y1 + (size_t)N * C_CH),
                       (const unsigned char*)nmask, flagA, flagB);
    hipLaunchKernelGGL(prep_k, dim3(2048), dim3(256), 0, stream,
                       feat, featb, N * C_CH / 4,
                       W1, Wp1, W2, Wp2);

    hipLaunchKernelGGL(conv_kernel, dim3(N / MTILE), dim3(256), 0, stream,
                       featb, Wp1, nidx, nmask, flagA, flagB, N, y1, S1, Q1);
    hipLaunchKernelGGL(finalize_bn_k, dim3(1), dim3(128), 0, stream, S1, Q1, g1, b1, sc1, bi1, 1.0f / N);
    hipLaunchKernelGGL(bn_relu_k, dim3(2048), dim3(256), 0, stream, y1, sc1, bi1, N * C_CH / 8);

    hipLaunchKernelGGL(conv_kernel, dim3(N / MTILE), dim3(256), 0, stream,
                       y1, Wp2, nidx, nmask, flagA, flagB, N, out2raw, S2, Q2);
    hipLaunchKernelGGL(finalize_bn_k, dim3(1), dim3(128), 0, stream, S2, Q2, g2, b2, sc2, bi2, 1.0f / N);
    hipLaunchKernelGGL(final_fuse_k, dim3(2048), dim3(256), 0, stream,
                       out2raw, feat, sc2, bi2, (float*)d_out, N * C_CH / 4);
}

// Round 12
// 549.274 us; speedup vs baseline: 1.5859x; 1.0103x over previous
//
#include <hip/hip_runtime.h>

// SparseBasicBlock: conv1(gather-GEMM) -> BN+ReLU -> conv2 -> BN -> +residual -> ReLU
// bf16 MFMA 16x16x32, fp32 accum. Conv: MTILE=64, 4 waves (col-split), 2 x 16KB
// LDS gather double-buffer (1-deep, staged post-barrier) + register-double-
// buffered B, exact counted vmcnt(8) + one raw s_barrier per ko, (256,3) so
// VGPR stays ~80 (R9's (256,4) forced 64 -> spill). Mask folded inline.

#define C_CH 128
#define K_OFF 9
#define MTILE 64

typedef __attribute__((ext_vector_type(8))) short bf16x8;
typedef __attribute__((ext_vector_type(4))) float f32x4;
typedef __attribute__((ext_vector_type(8))) unsigned short u16x8;

typedef __attribute__((address_space(1))) const unsigned int* gas_p;
typedef __attribute__((address_space(3))) unsigned int* las_p;

__device__ __forceinline__ void gload_lds16(const unsigned short* g, unsigned short* l) {
    __builtin_amdgcn_global_load_lds((gas_p)g, (las_p)l, 16, 0, 0);
}

__device__ __forceinline__ unsigned short f2b(float f) {
    union { float f; unsigned u; } v; v.f = f;
    unsigned r = v.u + 0x7fffu + ((v.u >> 16) & 1u);   // round-to-nearest-even
    return (unsigned short)(r >> 16);
}
__device__ __forceinline__ float b2f(unsigned short h) {
    union { unsigned u; float f; } v; v.u = ((unsigned)h) << 16;
    return v.f;
}

// ---------------- pre-kernels ----------------

// block 0: zero stats + flags + two zero-sentinel rows; blocks 1..64: detect mask dtype
__global__ void init_detect_k(float* stats, unsigned int* zrow1, unsigned int* zrow2,
                              const unsigned char* __restrict__ m, int* flagA, int* flagB) {
    int t = threadIdx.x;
    if (blockIdx.x == 0) {
        if (t < 256) { stats[t] = 0.f; stats[256 + t] = 0.f; }
        if (t >= 256 && t < 258) ((int*)stats)[1024 + (t - 256)] = 0;  // flagA, flagB
        if (t < 64) { zrow1[t] = 0u; zrow2[t] = 0u; }
    } else {
        int i = (blockIdx.x - 1) * 256 + t;   // first 16KB of mask
        unsigned char v = m[i];
        if ((i & 3) != 0 && v != 0) atomicOr(flagA, 1);
        if (v > 1) atomicOr(flagB, 1);
    }
}

// merged: convert feat->bf16 | pack W1,W2 (16x16 B-fragment layout)
// Wp[((ko*8+nt)*4+ks)*512 + lane*8 + j] = W[ko][ks*32+(lane>>4)*8+j][nt*16+(lane&15)]
__global__ void prep_k(const float* __restrict__ x, unsigned short* __restrict__ y, int n4,
                       const float* __restrict__ W1, unsigned short* __restrict__ Wp1,
                       const float* __restrict__ W2, unsigned short* __restrict__ Wp2) {
    const int PACK = K_OFF * 8 * 4 * 512;      // per-tensor packed elements
    int i = blockIdx.x * blockDim.x + threadIdx.x;
    int s = gridDim.x * blockDim.x;
    int tot = n4 + 2 * PACK;
    for (; i < tot; i += s) {
        if (i < n4) {
            float4 f = ((const float4*)x)[i];
            ushort4 o;
            o.x = f2b(f.x); o.y = f2b(f.y); o.z = f2b(f.z); o.w = f2b(f.w);
            ((ushort4*)y)[i] = o;
        } else {
            int ii = i - n4;
            const float* W = (ii < PACK) ? W1 : W2;
            unsigned short* Wp = (ii < PACK) ? Wp1 : Wp2;
            if (ii >= PACK) ii -= PACK;
            int j = ii & 7;
            int l = (ii >> 3) & 63;
            int frag = ii >> 9;
            int ks = frag & 3;
            int nt = (frag >> 2) & 7;
            int ko = frag >> 5;
            int cin = ks * 32 + (l >> 4) * 8 + j;
            int cout = nt * 16 + (l & 15);
            Wp[ii] = f2b(W[ko * C_CH * C_CH + cin * C_CH + cout]);
        }
    }
}

// ---------------- gather-GEMM conv ----------------

__global__ __launch_bounds__(256, 3) void conv_kernel(
    const unsigned short* __restrict__ Xb,   // (N+1) x 128 bf16 (row N = zeros)
    const unsigned short* __restrict__ Wp,   // packed weights (fragment layout)
    const int* __restrict__ nidx,            // N x 9 rulebook indices
    const void* __restrict__ nmask,          // N x 9 mask (dtype per flags)
    const int* __restrict__ flagA, const int* __restrict__ flagB,
    int Nzero,                               // zero-sentinel row index (= N)
    unsigned short* __restrict__ Yraw,       // N x 128 bf16 raw conv output
    float* __restrict__ statS, float* __restrict__ statQ)
{
    const int tid = threadIdx.x;
    const int lane = tid & 63;
    const int wv = tid >> 6;          // wave 0..3 owns cols [wv*32, wv*32+32)
    const int tile = blockIdx.x * MTILE;
    const int asub = lane >> 4;       // 0..3
    const int l15 = lane & 15;

    __shared__ alignas(16) unsigned short At[2][MTILE * C_CH]; // 2 x 16KB, linear
    __shared__ int sIdxT[K_OFF][MTILE];                        // 2.25KB

    // fold mask + idx inline (no separate eidx pass)
    {
        int fa = *flagA, fb = *flagB;
        for (int i = tid; i < MTILE * K_OFF; i += 256) {
            int r = i / K_OFF, k = i - r * K_OFF;
            size_t gi = (size_t)(tile + r) * K_OFF + k;
            bool t;
            if (!fa)       t = ((const int*)nmask)[gi] != 0;            // int32
            else if (fb)   t = ((const unsigned*)nmask)[gi] != 0;       // float32 bit test
            else           t = ((const unsigned char*)nmask)[gi] != 0;  // uint8 bool
            sIdxT[k][r] = t ? nidx[gi] : Nzero;
        }
    }
    __syncthreads();

    const int r_st = tid >> 4;      // 0..15
    const int ch_st = tid & 15;     // 0..15

    // STAGE(buf, ko): 4 async global->LDS 16B loads; LDS dest lane-linear
    // (gload_lds requirement); global source pre-XOR-swizzled so the swizzled
    // ds_read below recovers the right chunk.
    #define STAGE(buf, ko)                                                        \
        {                                                                         \
            _Pragma("unroll")                                                     \
            for (int jr = 0; jr < 4; ++jr) {                                      \
                int r = jr * 16 + r_st;                                           \
                int g = sIdxT[ko][r];                                             \
                const unsigned short* src =                                       \
                    Xb + (size_t)g * C_CH + ((ch_st ^ (r & 7)) * 8);              \
                unsigned short* dst = &At[buf][r * C_CH + ch_st * 8];             \
                gload_lds16(src, dst);                                            \
            }                                                                     \
        }

    // LOADB*(ko): 8 x 16B global loads of this wave's 2 col-tiles into named regs
    #define LOADB0(ko)                                                            \
        {                                                                         \
            const unsigned short* wb = Wp + (size_t)(ko) * (8 * 4 * 512) + lane * 8; \
            _Pragma("unroll")                                                     \
            for (int ks = 0; ks < 4; ++ks) {                                      \
                b0a[ks] = *(const bf16x8*)(wb + ((wv * 2 + 0) * 4 + ks) * 512);   \
                b0b[ks] = *(const bf16x8*)(wb + ((wv * 2 + 1) * 4 + ks) * 512);   \
            }                                                                     \
        }
    #define LOADB1(ko)                                                            \
        {                                                                         \
            const unsigned short* wb = Wp + (size_t)(ko) * (8 * 4 * 512) + lane * 8; \
            _Pragma("unroll")                                                     \
            for (int ks = 0; ks < 4; ++ks) {                                      \
                b1a[ks] = *(const bf16x8*)(wb + ((wv * 2 + 0) * 4 + ks) * 512);   \
                b1b[ks] = *(const bf16x8*)(wb + ((wv * 2 + 1) * 4 + ks) * 512);   \
            }                                                                     \
        }

    f32x4 acc[4][2];
    #pragma unroll
    for (int m = 0; m < 4; ++m) { acc[m][0] = (f32x4){0,0,0,0}; acc[m][1] = (f32x4){0,0,0,0}; }

    bf16x8 b0a[4], b0b[4], b1a[4], b1b[4];

    // prologue queue: s0(4) B0(8)
    STAGE(0, 0);
    LOADB0(0);

    // Per iteration KO (fully unrolled):
    //   [LOADB(KO+1) -> other parity regs] [sched_barrier]
    //   [s_waitcnt vmcnt(VM)] [s_barrier] [sched_barrier]
    //   [STAGE(KO+1) -> buf (KO+1)&1]  (that buf last read at iter KO-1; all
    //    waves crossed this iter's barrier after that read -> safe)
    //   [setprio(1): 16x ds_read A from buf KO&1 + 32 MFMA]
    // Queue at the wait: B(KO)8 s(KO)4 | B(KO+1)8 -> vmcnt(8) exact.
    // STAGE(KO+1) completion is covered by iter KO+1's vmcnt(8) (it drains
    // B(KO+1)+s(KO+1), leaving only B(KO+2)).
    #define CONV_ITER(KO, BA, BB, LB, VM)                                         \
        {                                                                         \
            if ((KO) + 1 < K_OFF) { LB((KO) + 1); }                               \
            __builtin_amdgcn_sched_barrier(0);                                    \
            asm volatile("s_waitcnt vmcnt(" #VM ")" ::: "memory");                \
            __builtin_amdgcn_s_barrier();                                         \
            __builtin_amdgcn_sched_barrier(0);                                    \
            if ((KO) + 1 < K_OFF) { STAGE((((KO) + 1) & 1), (KO) + 1); }          \
            __builtin_amdgcn_s_setprio(1);                                        \
            _Pragma("unroll")                                                     \
            for (int m = 0; m < 4; ++m) {                                         \
                bf16x8 a[4];                                                      \
                _Pragma("unroll")                                                 \
                for (int ks = 0; ks < 4; ++ks) {                                  \
                    int row = m * 16 + l15;                                       \
                    int sc = (ks * 4 + asub) ^ (row & 7);                         \
                    a[ks] = *(const bf16x8*)((const char*)At[(KO) & 1] + row * 256 + sc * 16); \
                }                                                                 \
                _Pragma("unroll")                                                 \
                for (int ks = 0; ks < 4; ++ks) {                                  \
                    acc[m][0] = __builtin_amdgcn_mfma_f32_16x16x32_bf16(a[ks], BA[ks], acc[m][0], 0, 0, 0); \
                    acc[m][1] = __builtin_amdgcn_mfma_f32_16x16x32_bf16(a[ks], BB[ks], acc[m][1], 0, 0, 0); \
                }                                                                 \
            }                                                                     \
            __builtin_amdgcn_s_setprio(0);                                        \
        }

    CONV_ITER(0, b0a, b0b, LOADB1, 8)
    CONV_ITER(1, b1a, b1b, LOADB0, 8)
    CONV_ITER(2, b0a, b0b, LOADB1, 8)
    CONV_ITER(3, b1a, b1b, LOADB0, 8)
    CONV_ITER(4, b0a, b0b, LOADB1, 8)
    CONV_ITER(5, b1a, b1b, LOADB0, 8)
    CONV_ITER(6, b0a, b0b, LOADB1, 8)
    CONV_ITER(7, b1a, b1b, LOADB0, 8)
    CONV_ITER(8, b0a, b0b, LOADB1, 0)
    #undef CONV_ITER
    #undef STAGE
    #undef LOADB0
    #undef LOADB1

    // ---- per-channel stats (each wave owns channels [wv*32, wv*32+32)) ----
    #pragma unroll
    for (int j = 0; j < 2; ++j) {
        float s = 0.f, q = 0.f;
        #pragma unroll
        for (int m = 0; m < 4; ++m)
            #pragma unroll
            for (int r = 0; r < 4; ++r) { float v = acc[m][j][r]; s += v; q += v * v; }
        s += __shfl_xor(s, 16); s += __shfl_xor(s, 32);
        q += __shfl_xor(q, 16); q += __shfl_xor(q, 32);
        if (lane < 16) {
            atomicAdd(&statS[wv * 32 + j * 16 + lane], s);
            atomicAdd(&statQ[wv * 32 + j * 16 + lane], q);
        }
    }

    // ---- write raw conv output (bf16) ----
    #pragma unroll
    for (int m = 0; m < 4; ++m)
        #pragma unroll
        for (int j = 0; j < 2; ++j) {
            int col = (wv * 2 + j) * 16 + l15;
            #pragma unroll
            for (int r = 0; r < 4; ++r) {
                int row = tile + m * 16 + asub * 4 + r;
                Yraw[(size_t)row * C_CH + col] = f2b(acc[m][j][r]);
            }
        }
}

// ---------------- BN finalize / apply ----------------

__global__ void finalize_bn_k(const float* __restrict__ S, const float* __restrict__ Q,
                              const float* __restrict__ gamma, const float* __restrict__ beta,
                              float* __restrict__ scale, float* __restrict__ bias, float invN) {
    int c = threadIdx.x;
    if (c < C_CH) {
        float mu = S[c] * invN;
        float var = Q[c] * invN - mu * mu;
        float inv = rsqrtf(var + 1e-4f);
        float sc = gamma[c] * inv;
        scale[c] = sc;
        bias[c] = beta[c] - mu * sc;
    }
}

__global__ void bn_relu_k(unsigned short* __restrict__ y,
                          const float* __restrict__ scale, const float* __restrict__ bias, int n8) {
    int i0 = blockIdx.x * blockDim.x + threadIdx.x;
    int S = gridDim.x * blockDim.x;
    int c0 = (i0 * 8) & (C_CH - 1);
    float sc[8], bs[8];
    #pragma unroll
    for (int j = 0; j < 8; ++j) { sc[j] = scale[c0 + j]; bs[j] = bias[c0 + j]; }
    for (int i = i0; i < n8; i += S) {
        u16x8 v = ((const u16x8*)y)[i];
        #pragma unroll
        for (int j = 0; j < 8; ++j) {
            float x = b2f((unsigned short)v[j]);
            x = fmaxf(x * sc[j] + bs[j], 0.f);
            v[j] = (short)f2b(x);
        }
        ((u16x8*)y)[i] = v;
    }
}

__global__ void final_fuse_k(const unsigned short* __restrict__ raw,
                             const float* __restrict__ feat,
                             const float* __restrict__ scale, const float* __restrict__ bias,
                             float* __restrict__ out, int n4) {
    int i0 = blockIdx.x * blockDim.x + threadIdx.x;
    int S = gridDim.x * blockDim.x;
    int c0 = (i0 * 4) & (C_CH - 1);
    float sc[4], bs[4];
    #pragma unroll
    for (int j = 0; j < 4; ++j) { sc[j] = scale[c0 + j]; bs[j] = bias[c0 + j]; }
    for (int i = i0; i < n4; i += S) {
        ushort4 r = ((const ushort4*)raw)[i];
        float4 f = ((const float4*)feat)[i];
        float4 o;
        o.x = fmaxf(b2f(r.x) * sc[0] + bs[0] + f.x, 0.f);
        o.y = fmaxf(b2f(r.y) * sc[1] + bs[1] + f.y, 0.f);
        o.z = fmaxf(b2f(r.z) * sc[2] + bs[2] + f.z, 0.f);
        o.w = fmaxf(b2f(r.w) * sc[3] + bs[3] + f.w, 0.f);
        ((float4*)out)[i] = o;
    }
}

// ---------------- launch ----------------

extern "C" void kernel_launch(void* const* d_in, const int* in_sizes, int n_in,
                              void* d_out, int out_size, void* d_ws, size_t ws_size,
                              hipStream_t stream) {
    const float* feat = (const float*)d_in[0];
    const float* W1 = (const float*)d_in[1];
    const float* W2 = (const float*)d_in[2];
    const float* g1 = (const float*)d_in[3];
    const float* b1 = (const float*)d_in[4];
    const float* g2 = (const float*)d_in[5];
    const float* b2 = (const float*)d_in[6];
    const int* nidx = (const int*)d_in[7];
    const void* nmask = d_in[8];

    const int N = in_sizes[0] / C_CH;   // 400000

    char* ws = (char*)d_ws;
    unsigned short* featb = (unsigned short*)ws;                          // (N+1) x 128 bf16
    size_t off = (size_t)(N + 1) * C_CH * 2;
    off = (off + 255) & ~(size_t)255;
    unsigned short* Wp1 = (unsigned short*)(ws + off); off += (size_t)K_OFF * C_CH * C_CH * 2;
    unsigned short* Wp2 = (unsigned short*)(ws + off); off += (size_t)K_OFF * C_CH * C_CH * 2;
    float* stats = (float*)(ws + off);
    float* S1 = stats;        float* Q1 = stats + 128;
    float* S2 = stats + 256;  float* Q2 = stats + 384;
    float* sc1 = stats + 512; float* bi1 = stats + 640;
    float* sc2 = stats + 768; float* bi2 = stats + 896;
    int* flagA = ((int*)stats) + 1024;
    int* flagB = ((int*)stats) + 1025;

    // scratch inside d_out: y1 = rows [0, N] bf16 (~102.4MB); rewritten by final_fuse.
    unsigned short* y1 = (unsigned short*)d_out;
    unsigned short* out2raw = featb;               // reuse feat-bf16 region after conv1

    hipLaunchKernelGGL(init_detect_k, dim3(65), dim3(256), 0, stream,
                       stats, (unsigned int*)(featb + (size_t)N * C_CH),
                       (unsigned int*)(y1 + (size_t)N * C_CH),
                       (const unsigned char*)nmask, flagA, flagB);
    hipLaunchKernelGGL(prep_k, dim3(2048), dim3(256), 0, stream,
                       feat, featb, N * C_CH / 4,
                       W1, Wp1, W2, Wp2);

    hipLaunchKernelGGL(conv_kernel, dim3(N / MTILE), dim3(256), 0, stream,
                       featb, Wp1, nidx, nmask, flagA, flagB, N, y1, S1, Q1);
    hipLaunchKernelGGL(finalize_bn_k, dim3(1), dim3(128), 0, stream, S1, Q1, g1, b1, sc1, bi1, 1.0f / N);
    hipLaunchKernelGGL(bn_relu_k, dim3(2048), dim3(256), 0, stream, y1, sc1, bi1, N * C_CH / 8);

    hipLaunchKernelGGL(conv_kernel, dim3(N / MTILE), dim3(256), 0, stream,
                       y1, Wp2, nidx, nmask, flagA, flagB, N, out2raw, S2, Q2);
    hipLaunchKernelGGL(finalize_bn_k, dim3(1), dim3(128), 0, stream, S2, Q2, g2, b2, sc2, bi2, 1.0f / N);
    hipLaunchKernelGGL(final_fuse_k, dim3(2048), dim3(256), 0, stream,
                       out2raw, feat, sc2, bi2, (float*)d_out, N * C_CH / 4);
}

// Round 14
// 531.118 us; speedup vs baseline: 1.6401x; 1.0342x over previous
//
#include <hip/hip_runtime.h>

// SparseBasicBlock: conv1(gather-GEMM) -> BN+ReLU -> conv2 -> BN -> +residual -> ReLU
// bf16 MFMA 16x16x32, fp32 accum. Conv: MTILE=64, 4 waves (col-split), 2 x 16KB
// LDS gather double-buffer (1-deep) via global_load_lds + register-double-
// buffered B, exact counted vmcnt(8) + one raw s_barrier per ko.
// R14: R13 with nontemporal builtins on ext_vector types (struct float4/ushort4
// are invalid operands -> compile fix) + clamped dead STAGE indices.

#define C_CH 128
#define K_OFF 9
#define MTILE 64

typedef __attribute__((ext_vector_type(8))) short bf16x8;
typedef __attribute__((ext_vector_type(4))) float f32x4;
typedef __attribute__((ext_vector_type(4))) unsigned short u16x4;
typedef __attribute__((ext_vector_type(8))) unsigned short u16x8;

typedef __attribute__((address_space(1))) const unsigned int* gas_p;
typedef __attribute__((address_space(3))) unsigned int* las_p;

__device__ __forceinline__ void gload_lds16(const unsigned short* g, unsigned short* l) {
    __builtin_amdgcn_global_load_lds((gas_p)g, (las_p)l, 16, 0, 0);
}

__device__ __forceinline__ unsigned short f2b(float f) {
    union { float f; unsigned u; } v; v.f = f;
    unsigned r = v.u + 0x7fffu + ((v.u >> 16) & 1u);   // round-to-nearest-even
    return (unsigned short)(r >> 16);
}
__device__ __forceinline__ float b2f(unsigned short h) {
    union { unsigned u; float f; } v; v.u = ((unsigned)h) << 16;
    return v.f;
}

// ---------------- pre-kernels ----------------

// block 0: zero stats + flags + two zero-sentinel rows; blocks 1..64: detect mask dtype
__global__ void init_detect_k(float* stats, unsigned int* zrow1, unsigned int* zrow2,
                              const unsigned char* __restrict__ m, int* flagA, int* flagB) {
    int t = threadIdx.x;
    if (blockIdx.x == 0) {
        if (t < 256) { stats[t] = 0.f; stats[256 + t] = 0.f; }
        if (t >= 256 && t < 258) ((int*)stats)[1024 + (t - 256)] = 0;  // flagA, flagB
        if (t < 64) { zrow1[t] = 0u; zrow2[t] = 0u; }
    } else {
        int i = (blockIdx.x - 1) * 256 + t;   // first 16KB of mask
        unsigned char v = m[i];
        if ((i & 3) != 0 && v != 0) atomicOr(flagA, 1);
        if (v > 1) atomicOr(flagB, 1);
    }
}

// merged: convert feat->bf16 | pack W1,W2 (16x16 B-fragment layout)
// Wp[((ko*8+nt)*4+ks)*512 + lane*8 + j] = W[ko][ks*32+(lane>>4)*8+j][nt*16+(lane&15)]
__global__ void prep_k(const float* __restrict__ x, unsigned short* __restrict__ y, int n4,
                       const float* __restrict__ W1, unsigned short* __restrict__ Wp1,
                       const float* __restrict__ W2, unsigned short* __restrict__ Wp2) {
    const int PACK = K_OFF * 8 * 4 * 512;      // per-tensor packed elements
    int i = blockIdx.x * blockDim.x + threadIdx.x;
    int s = gridDim.x * blockDim.x;
    int tot = n4 + 2 * PACK;
    for (; i < tot; i += s) {
        if (i < n4) {
            f32x4 f = __builtin_nontemporal_load((const f32x4*)x + i);
            u16x4 o;
            o[0] = f2b(f[0]); o[1] = f2b(f[1]); o[2] = f2b(f[2]); o[3] = f2b(f[3]);
            ((u16x4*)y)[i] = o;              // normal store: featb should be L3-hot
        } else {
            int ii = i - n4;
            const float* W = (ii < PACK) ? W1 : W2;
            unsigned short* Wp = (ii < PACK) ? Wp1 : Wp2;
            if (ii >= PACK) ii -= PACK;
            int j = ii & 7;
            int l = (ii >> 3) & 63;
            int frag = ii >> 9;
            int ks = frag & 3;
            int nt = (frag >> 2) & 7;
            int ko = frag >> 5;
            int cin = ks * 32 + (l >> 4) * 8 + j;
            int cout = nt * 16 + (l & 15);
            Wp[ii] = f2b(W[ko * C_CH * C_CH + cin * C_CH + cout]);
        }
    }
}

// ---------------- gather-GEMM conv ----------------

template <bool NTOUT>
__global__ __launch_bounds__(256, 3) void conv_kernel(
    const unsigned short* __restrict__ Xb,   // (N+1) x 128 bf16 (row N = zeros)
    const unsigned short* __restrict__ Wp,   // packed weights (fragment layout)
    const int* __restrict__ nidx,            // N x 9 rulebook indices
    const void* __restrict__ nmask,          // N x 9 mask (dtype per flags)
    const int* __restrict__ flagA, const int* __restrict__ flagB,
    int Nzero,                               // zero-sentinel row index (= N)
    unsigned short* __restrict__ Yraw,       // N x 128 bf16 raw conv output
    float* __restrict__ statS, float* __restrict__ statQ)
{
    const int tid = threadIdx.x;
    const int lane = tid & 63;
    const int wv = tid >> 6;          // wave 0..3 owns cols [wv*32, wv*32+32)
    const int tile = blockIdx.x * MTILE;
    const int asub = lane >> 4;       // 0..3
    const int l15 = lane & 15;

    __shared__ alignas(16) unsigned short At[2][MTILE * C_CH]; // 2 x 16KB, linear
    __shared__ int sIdxT[K_OFF][MTILE];                        // 2.25KB

    // fold mask + idx inline; rulebook via nt-loads (read-once, keep L3 clean)
    {
        int fa = *flagA, fb = *flagB;
        for (int i = tid; i < MTILE * K_OFF; i += 256) {
            int r = i / K_OFF, k = i - r * K_OFF;
            size_t gi = (size_t)(tile + r) * K_OFF + k;
            bool t;
            if (!fa)       t = __builtin_nontemporal_load((const int*)nmask + gi) != 0;
            else if (fb)   t = __builtin_nontemporal_load((const unsigned*)nmask + gi) != 0;
            else           t = __builtin_nontemporal_load((const unsigned char*)nmask + gi) != 0;
            sIdxT[k][r] = t ? __builtin_nontemporal_load(nidx + gi) : Nzero;
        }
    }
    __syncthreads();

    const int r_st = tid >> 4;      // 0..15
    const int ch_st = tid & 15;     // 0..15

    #define STAGE(buf, ko)                                                        \
        {                                                                         \
            _Pragma("unroll")                                                     \
            for (int jr = 0; jr < 4; ++jr) {                                      \
                int r = jr * 16 + r_st;                                           \
                int g = sIdxT[ko][r];                                             \
                const unsigned short* src =                                       \
                    Xb + (size_t)g * C_CH + ((ch_st ^ (r & 7)) * 8);              \
                unsigned short* dst = &At[buf][r * C_CH + ch_st * 8];             \
                gload_lds16(src, dst);                                            \
            }                                                                     \
        }

    #define LOADB0(ko)                                                            \
        {                                                                         \
            const unsigned short* wb = Wp + (size_t)(ko) * (8 * 4 * 512) + lane * 8; \
            _Pragma("unroll")                                                     \
            for (int ks = 0; ks < 4; ++ks) {                                      \
                b0a[ks] = *(const bf16x8*)(wb + ((wv * 2 + 0) * 4 + ks) * 512);   \
                b0b[ks] = *(const bf16x8*)(wb + ((wv * 2 + 1) * 4 + ks) * 512);   \
            }                                                                     \
        }
    #define LOADB1(ko)                                                            \
        {                                                                         \
            const unsigned short* wb = Wp + (size_t)(ko) * (8 * 4 * 512) + lane * 8; \
            _Pragma("unroll")                                                     \
            for (int ks = 0; ks < 4; ++ks) {                                      \
                b1a[ks] = *(const bf16x8*)(wb + ((wv * 2 + 0) * 4 + ks) * 512);   \
                b1b[ks] = *(const bf16x8*)(wb + ((wv * 2 + 1) * 4 + ks) * 512);   \
            }                                                                     \
        }

    f32x4 acc[4][2];
    #pragma unroll
    for (int m = 0; m < 4; ++m) { acc[m][0] = (f32x4){0,0,0,0}; acc[m][1] = (f32x4){0,0,0,0}; }

    bf16x8 b0a[4], b0b[4], b1a[4], b1b[4];

    // prologue queue: s0(4) B0(8)
    STAGE(0, 0);
    LOADB0(0);

    // Queue at the wait: B(KO)8 s(KO)4 | B(KO+1)8 -> vmcnt(8) exact.
    // Guarded STAGE index clamped with % K_OFF (dead at KO=8; silences
    // -Warray-bounds on the constant-folded sIdxT[9]).
    #define CONV_ITER(KO, BA, BB, LB, VM)                                         \
        {                                                                         \
            if ((KO) + 1 < K_OFF) { LB((((KO) + 1) % K_OFF)); }                   \
            __builtin_amdgcn_sched_barrier(0);                                    \
            asm volatile("s_waitcnt vmcnt(" #VM ")" ::: "memory");                \
            __builtin_amdgcn_s_barrier();                                         \
            __builtin_amdgcn_sched_barrier(0);                                    \
            if ((KO) + 1 < K_OFF) { STAGE((((KO) + 1) & 1), (((KO) + 1) % K_OFF)); } \
            __builtin_amdgcn_s_setprio(1);                                        \
            _Pragma("unroll")                                                     \
            for (int m = 0; m < 4; ++m) {                                         \
                bf16x8 a[4];                                                      \
                _Pragma("unroll")                                                 \
                for (int ks = 0; ks < 4; ++ks) {                                  \
                    int row = m * 16 + l15;                                       \
                    int sc = (ks * 4 + asub) ^ (row & 7);                         \
                    a[ks] = *(const bf16x8*)((const char*)At[(KO) & 1] + row * 256 + sc * 16); \
                }                                                                 \
                _Pragma("unroll")                                                 \
                for (int ks = 0; ks < 4; ++ks) {                                  \
                    acc[m][0] = __builtin_amdgcn_mfma_f32_16x16x32_bf16(a[ks], BA[ks], acc[m][0], 0, 0, 0); \
                    acc[m][1] = __builtin_amdgcn_mfma_f32_16x16x32_bf16(a[ks], BB[ks], acc[m][1], 0, 0, 0); \
                }                                                                 \
            }                                                                     \
            __builtin_amdgcn_s_setprio(0);                                        \
        }

    CONV_ITER(0, b0a, b0b, LOADB1, 8)
    CONV_ITER(1, b1a, b1b, LOADB0, 8)
    CONV_ITER(2, b0a, b0b, LOADB1, 8)
    CONV_ITER(3, b1a, b1b, LOADB0, 8)
    CONV_ITER(4, b0a, b0b, LOADB1, 8)
    CONV_ITER(5, b1a, b1b, LOADB0, 8)
    CONV_ITER(6, b0a, b0b, LOADB1, 8)
    CONV_ITER(7, b1a, b1b, LOADB0, 8)
    CONV_ITER(8, b0a, b0b, LOADB1, 0)
    #undef CONV_ITER
    #undef STAGE
    #undef LOADB0
    #undef LOADB1

    // ---- per-channel stats (each wave owns channels [wv*32, wv*32+32)) ----
    #pragma unroll
    for (int j = 0; j < 2; ++j) {
        float s = 0.f, q = 0.f;
        #pragma unroll
        for (int m = 0; m < 4; ++m)
            #pragma unroll
            for (int r = 0; r < 4; ++r) { float v = acc[m][j][r]; s += v; q += v * v; }
        s += __shfl_xor(s, 16); s += __shfl_xor(s, 32);
        q += __shfl_xor(q, 16); q += __shfl_xor(q, 32);
        if (lane < 16) {
            atomicAdd(&statS[wv * 32 + j * 16 + lane], s);
            atomicAdd(&statQ[wv * 32 + j * 16 + lane], q);
        }
    }

    // ---- write raw conv output (bf16); nt when consumer is far (conv2) ----
    #pragma unroll
    for (int m = 0; m < 4; ++m)
        #pragma unroll
        for (int j = 0; j < 2; ++j) {
            int col = (wv * 2 + j) * 16 + l15;
            #pragma unroll
            for (int r = 0; r < 4; ++r) {
                int row = tile + m * 16 + asub * 4 + r;
                unsigned short v = f2b(acc[m][j][r]);
                if (NTOUT) __builtin_nontemporal_store(v, &Yraw[(size_t)row * C_CH + col]);
                else       Yraw[(size_t)row * C_CH + col] = v;
            }
        }
}

// ---------------- BN finalize / apply ----------------

__global__ void finalize_bn_k(const float* __restrict__ S, const float* __restrict__ Q,
                              const float* __restrict__ gamma, const float* __restrict__ beta,
                              float* __restrict__ scale, float* __restrict__ bias, float invN) {
    int c = threadIdx.x;
    if (c < C_CH) {
        float mu = S[c] * invN;
        float var = Q[c] * invN - mu * mu;
        float inv = rsqrtf(var + 1e-4f);
        float sc = gamma[c] * inv;
        scale[c] = sc;
        bias[c] = beta[c] - mu * sc;
    }
}

__global__ void bn_relu_k(unsigned short* __restrict__ y,
                          const float* __restrict__ scale, const float* __restrict__ bias, int n8) {
    int i0 = blockIdx.x * blockDim.x + threadIdx.x;
    int S = gridDim.x * blockDim.x;
    int c0 = (i0 * 8) & (C_CH - 1);
    float sc[8], bs[8];
    #pragma unroll
    for (int j = 0; j < 8; ++j) { sc[j] = scale[c0 + j]; bs[j] = bias[c0 + j]; }
    for (int i = i0; i < n8; i += S) {
        u16x8 v = ((const u16x8*)y)[i];
        #pragma unroll
        for (int j = 0; j < 8; ++j) {
            float x = b2f((unsigned short)v[j]);
            x = fmaxf(x * sc[j] + bs[j], 0.f);
            v[j] = (unsigned short)f2b(x);
        }
        ((u16x8*)y)[i] = v;   // stays L3-hot for conv2's gather
    }
}

// BF16RES: residual from bf16 featb (saves 102MB) when ws had room for out2raw.
template <bool BF16RES>
__global__ void final_fuse_k(const unsigned short* __restrict__ raw,
                             const float* __restrict__ featf,
                             const unsigned short* __restrict__ featb,
                             const float* __restrict__ scale, const float* __restrict__ bias,
                             float* __restrict__ out, int n4) {
    int i0 = blockIdx.x * blockDim.x + threadIdx.x;
    int S = gridDim.x * blockDim.x;
    int c0 = (i0 * 4) & (C_CH - 1);
    float sc[4], bs[4];
    #pragma unroll
    for (int j = 0; j < 4; ++j) { sc[j] = scale[c0 + j]; bs[j] = bias[c0 + j]; }
    for (int i = i0; i < n4; i += S) {
        u16x4 r = __builtin_nontemporal_load((const u16x4*)raw + i);
        float fx, fy, fz, fw;
        if (BF16RES) {
            u16x4 f = __builtin_nontemporal_load((const u16x4*)featb + i);
            fx = b2f(f[0]); fy = b2f(f[1]); fz = b2f(f[2]); fw = b2f(f[3]);
        } else {
            f32x4 f = __builtin_nontemporal_load((const f32x4*)featf + i);
            fx = f[0]; fy = f[1]; fz = f[2]; fw = f[3];
        }
        f32x4 o;
        o[0] = fmaxf(b2f(r[0]) * sc[0] + bs[0] + fx, 0.f);
        o[1] = fmaxf(b2f(r[1]) * sc[1] + bs[1] + fy, 0.f);
        o[2] = fmaxf(b2f(r[2]) * sc[2] + bs[2] + fz, 0.f);
        o[3] = fmaxf(b2f(r[3]) * sc[3] + bs[3] + fw, 0.f);
        __builtin_nontemporal_store(o, (f32x4*)out + i);
    }
}

// ---------------- launch ----------------

extern "C" void kernel_launch(void* const* d_in, const int* in_sizes, int n_in,
                              void* d_out, int out_size, void* d_ws, size_t ws_size,
                              hipStream_t stream) {
    const float* feat = (const float*)d_in[0];
    const float* W1 = (const float*)d_in[1];
    const float* W2 = (const float*)d_in[2];
    const float* g1 = (const float*)d_in[3];
    const float* b1 = (const float*)d_in[4];
    const float* g2 = (const float*)d_in[5];
    const float* b2 = (const float*)d_in[6];
    const int* nidx = (const int*)d_in[7];
    const void* nmask = d_in[8];

    const int N = in_sizes[0] / C_CH;   // 400000

    char* ws = (char*)d_ws;
    unsigned short* featb = (unsigned short*)ws;                          // (N+1) x 128 bf16
    size_t off = (size_t)(N + 1) * C_CH * 2;
    off = (off + 255) & ~(size_t)255;
    unsigned short* Wp1 = (unsigned short*)(ws + off); off += (size_t)K_OFF * C_CH * C_CH * 2;
    unsigned short* Wp2 = (unsigned short*)(ws + off); off += (size_t)K_OFF * C_CH * C_CH * 2;
    float* stats = (float*)(ws + off);
    float* S1 = stats;        float* Q1 = stats + 128;
    float* S2 = stats + 256;  float* Q2 = stats + 384;
    float* sc1 = stats + 512; float* bi1 = stats + 640;
    float* sc2 = stats + 768; float* bi2 = stats + 896;
    int* flagA = ((int*)stats) + 1024;
    int* flagB = ((int*)stats) + 1025;
    size_t off2 = off + 8192;   // end of stats region, aligned

    // conv2 output: separate ws region if it fits (keeps featb alive for bf16
    // residual); else overwrite featb (f32-feat residual fallback).
    size_t rawBytes = (size_t)N * C_CH * 2;
    bool sepOut = (ws_size >= off2 + rawBytes);
    unsigned short* out2raw = sepOut ? (unsigned short*)(ws + off2) : featb;

    // scratch inside d_out: y1 = rows [0, N] bf16 (~102.4MB); rewritten by final_fuse.
    unsigned short* y1 = (unsigned short*)d_out;

    hipLaunchKernelGGL(init_detect_k, dim3(65), dim3(256), 0, stream,
                       stats, (unsigned int*)(featb + (size_t)N * C_CH),
                       (unsigned int*)(y1 + (size_t)N * C_CH),
                       (const unsigned char*)nmask, flagA, flagB);
    hipLaunchKernelGGL(prep_k, dim3(2048), dim3(256), 0, stream,
                       feat, featb, N * C_CH / 4,
                       W1, Wp1, W2, Wp2);

    hipLaunchKernelGGL(conv_kernel<false>, dim3(N / MTILE), dim3(256), 0, stream,
                       featb, Wp1, nidx, nmask, flagA, flagB, N, y1, S1, Q1);
    hipLaunchKernelGGL(finalize_bn_k, dim3(1), dim3(128), 0, stream, S1, Q1, g1, b1, sc1, bi1, 1.0f / N);
    hipLaunchKernelGGL(bn_relu_k, dim3(2048), dim3(256), 0, stream, y1, sc1, bi1, N * C_CH / 8);

    hipLaunchKernelGGL(conv_kernel<true>, dim3(N / MTILE), dim3(256), 0, stream,
                       y1, Wp2, nidx, nmask, flagA, flagB, N, out2raw, S2, Q2);
    hipLaunchKernelGGL(finalize_bn_k, dim3(1), dim3(128), 0, stream, S2, Q2, g2, b2, sc2, bi2, 1.0f / N);
    if (sepOut) {
        hipLaunchKernelGGL(final_fuse_k<true>, dim3(2048), dim3(256), 0, stream,
                           out2raw, feat, featb, sc2, bi2, (float*)d_out, N * C_CH / 4);
    } else {
        hipLaunchKernelGGL(final_fuse_k<false>, dim3(2048), dim3(256), 0, stream,
                           out2raw, feat, featb, sc2, bi2, (float*)d_out, N * C_CH / 4);
    }
}

// Round 15
// 524.118 us; speedup vs baseline: 1.6620x; 1.0134x over previous
//
#include <hip/hip_runtime.h>

// SparseBasicBlock: conv1(gather-GEMM) -> BN+ReLU -> conv2 -> BN -> +residual -> ReLU
// bf16 MFMA 16x16x32, fp32 accum. Conv: MTILE=64, 4 waves (col-split), 2 x 16KB
// LDS gather double-buffer (1-deep) via global_load_lds + register-double-
// buffered B, exact counted vmcnt(8) + one raw s_barrier per ko.
// R15: plain conv stores (nt 2B stores caused +59MB write amplification),
// init/detect merged into prep, bf16 residual + nt aux loads kept.

#define C_CH 128
#define K_OFF 9
#define MTILE 64

typedef __attribute__((ext_vector_type(8))) short bf16x8;
typedef __attribute__((ext_vector_type(4))) float f32x4;
typedef __attribute__((ext_vector_type(4))) unsigned short u16x4;
typedef __attribute__((ext_vector_type(8))) unsigned short u16x8;

typedef __attribute__((address_space(1))) const unsigned int* gas_p;
typedef __attribute__((address_space(3))) unsigned int* las_p;

__device__ __forceinline__ void gload_lds16(const unsigned short* g, unsigned short* l) {
    __builtin_amdgcn_global_load_lds((gas_p)g, (las_p)l, 16, 0, 0);
}

__device__ __forceinline__ unsigned short f2b(float f) {
    union { float f; unsigned u; } v; v.f = f;
    unsigned r = v.u + 0x7fffu + ((v.u >> 16) & 1u);   // round-to-nearest-even
    return (unsigned short)(r >> 16);
}
__device__ __forceinline__ float b2f(unsigned short h) {
    union { unsigned u; float f; } v; v.u = ((unsigned)h) << 16;
    return v.f;
}

// ---------------- prep (merged init + detect + convert + pack) ----------------
// block 0: zero stats/flags + two zero-sentinel rows
// blocks 1..64: detect mask dtype from first 16KB
// all blocks: grid-stride {feat->bf16 convert | W1,W2 pack}
// Wp[((ko*8+nt)*4+ks)*512 + lane*8 + j] = W[ko][ks*32+(lane>>4)*8+j][nt*16+(lane&15)]
__global__ void prep_k(const float* __restrict__ x, unsigned short* __restrict__ y, int n4,
                       const float* __restrict__ W1, unsigned short* __restrict__ Wp1,
                       const float* __restrict__ W2, unsigned short* __restrict__ Wp2,
                       float* stats, unsigned int* zrow1, unsigned int* zrow2,
                       const unsigned char* __restrict__ m, int* flagA, int* flagB) {
    const int t = threadIdx.x;
    if (blockIdx.x == 0) {
        if (t < 256) { stats[t] = 0.f; stats[256 + t] = 0.f; }
        if (t >= 256 && t < 258) ((int*)stats)[1024 + (t - 256)] = 0;  // flagA, flagB
        if (t < 64) { zrow1[t] = 0u; zrow2[t] = 0u; }
    } else if (blockIdx.x <= 64) {
        int i = (blockIdx.x - 1) * 256 + t;   // first 16KB of mask
        unsigned char v = m[i];
        if ((i & 3) != 0 && v != 0) atomicOr(flagA, 1);
        if (v > 1) atomicOr(flagB, 1);
    }
    const int PACK = K_OFF * 8 * 4 * 512;      // per-tensor packed elements
    int i = blockIdx.x * blockDim.x + t;
    int s = gridDim.x * blockDim.x;
    int tot = n4 + 2 * PACK;
    for (; i < tot; i += s) {
        if (i < n4) {
            f32x4 f = __builtin_nontemporal_load((const f32x4*)x + i);
            u16x4 o;
            o[0] = f2b(f[0]); o[1] = f2b(f[1]); o[2] = f2b(f[2]); o[3] = f2b(f[3]);
            ((u16x4*)y)[i] = o;              // normal store: featb should be L3-hot
        } else {
            int ii = i - n4;
            const float* W = (ii < PACK) ? W1 : W2;
            unsigned short* Wp = (ii < PACK) ? Wp1 : Wp2;
            if (ii >= PACK) ii -= PACK;
            int j = ii & 7;
            int l = (ii >> 3) & 63;
            int frag = ii >> 9;
            int ks = frag & 3;
            int nt = (frag >> 2) & 7;
            int ko = frag >> 5;
            int cin = ks * 32 + (l >> 4) * 8 + j;
            int cout = nt * 16 + (l & 15);
            Wp[ii] = f2b(W[ko * C_CH * C_CH + cin * C_CH + cout]);
        }
    }
}

// ---------------- gather-GEMM conv ----------------

__global__ __launch_bounds__(256, 3) void conv_kernel(
    const unsigned short* __restrict__ Xb,   // (N+1) x 128 bf16 (row N = zeros)
    const unsigned short* __restrict__ Wp,   // packed weights (fragment layout)
    const int* __restrict__ nidx,            // N x 9 rulebook indices
    const void* __restrict__ nmask,          // N x 9 mask (dtype per flags)
    const int* __restrict__ flagA, const int* __restrict__ flagB,
    int Nzero,                               // zero-sentinel row index (= N)
    unsigned short* __restrict__ Yraw,       // N x 128 bf16 raw conv output
    float* __restrict__ statS, float* __restrict__ statQ)
{
    const int tid = threadIdx.x;
    const int lane = tid & 63;
    const int wv = tid >> 6;          // wave 0..3 owns cols [wv*32, wv*32+32)
    const int tile = blockIdx.x * MTILE;
    const int asub = lane >> 4;       // 0..3
    const int l15 = lane & 15;

    __shared__ alignas(16) unsigned short At[2][MTILE * C_CH]; // 2 x 16KB, linear
    __shared__ int sIdxT[K_OFF][MTILE];                        // 2.25KB

    // fold mask + idx inline; rulebook via nt-loads (read-once, keep L3 clean)
    {
        int fa = *flagA, fb = *flagB;
        for (int i = tid; i < MTILE * K_OFF; i += 256) {
            int r = i / K_OFF, k = i - r * K_OFF;
            size_t gi = (size_t)(tile + r) * K_OFF + k;
            bool t;
            if (!fa)       t = __builtin_nontemporal_load((const int*)nmask + gi) != 0;
            else if (fb)   t = __builtin_nontemporal_load((const unsigned*)nmask + gi) != 0;
            else           t = __builtin_nontemporal_load((const unsigned char*)nmask + gi) != 0;
            sIdxT[k][r] = t ? __builtin_nontemporal_load(nidx + gi) : Nzero;
        }
    }
    __syncthreads();

    const int r_st = tid >> 4;      // 0..15
    const int ch_st = tid & 15;     // 0..15

    #define STAGE(buf, ko)                                                        \
        {                                                                         \
            _Pragma("unroll")                                                     \
            for (int jr = 0; jr < 4; ++jr) {                                      \
                int r = jr * 16 + r_st;                                           \
                int g = sIdxT[ko][r];                                             \
                const unsigned short* src =                                       \
                    Xb + (size_t)g * C_CH + ((ch_st ^ (r & 7)) * 8);              \
                unsigned short* dst = &At[buf][r * C_CH + ch_st * 8];             \
                gload_lds16(src, dst);                                            \
            }                                                                     \
        }

    #define LOADB0(ko)                                                            \
        {                                                                         \
            const unsigned short* wb = Wp + (size_t)(ko) * (8 * 4 * 512) + lane * 8; \
            _Pragma("unroll")                                                     \
            for (int ks = 0; ks < 4; ++ks) {                                      \
                b0a[ks] = *(const bf16x8*)(wb + ((wv * 2 + 0) * 4 + ks) * 512);   \
                b0b[ks] = *(const bf16x8*)(wb + ((wv * 2 + 1) * 4 + ks) * 512);   \
            }                                                                     \
        }
    #define LOADB1(ko)                                                            \
        {                                                                         \
            const unsigned short* wb = Wp + (size_t)(ko) * (8 * 4 * 512) + lane * 8; \
            _Pragma("unroll")                                                     \
            for (int ks = 0; ks < 4; ++ks) {                                      \
                b1a[ks] = *(const bf16x8*)(wb + ((wv * 2 + 0) * 4 + ks) * 512);   \
                b1b[ks] = *(const bf16x8*)(wb + ((wv * 2 + 1) * 4 + ks) * 512);   \
            }                                                                     \
        }

    f32x4 acc[4][2];
    #pragma unroll
    for (int m = 0; m < 4; ++m) { acc[m][0] = (f32x4){0,0,0,0}; acc[m][1] = (f32x4){0,0,0,0}; }

    bf16x8 b0a[4], b0b[4], b1a[4], b1b[4];

    // prologue queue: s0(4) B0(8)
    STAGE(0, 0);
    LOADB0(0);

    // Queue at the wait: B(KO)8 s(KO)4 | B(KO+1)8 -> vmcnt(8) exact.
    // Guarded STAGE/LOADB indices clamped with % K_OFF (dead at KO=8).
    #define CONV_ITER(KO, BA, BB, LB, VM)                                         \
        {                                                                         \
            if ((KO) + 1 < K_OFF) { LB((((KO) + 1) % K_OFF)); }                   \
            __builtin_amdgcn_sched_barrier(0);                                    \
            asm volatile("s_waitcnt vmcnt(" #VM ")" ::: "memory");                \
            __builtin_amdgcn_s_barrier();                                         \
            __builtin_amdgcn_sched_barrier(0);                                    \
            if ((KO) + 1 < K_OFF) { STAGE((((KO) + 1) & 1), (((KO) + 1) % K_OFF)); } \
            __builtin_amdgcn_s_setprio(1);                                        \
            _Pragma("unroll")                                                     \
            for (int m = 0; m < 4; ++m) {                                         \
                bf16x8 a[4];                                                      \
                _Pragma("unroll")                                                 \
                for (int ks = 0; ks < 4; ++ks) {                                  \
                    int row = m * 16 + l15;                                       \
                    int sc = (ks * 4 + asub) ^ (row & 7);                         \
                    a[ks] = *(const bf16x8*)((const char*)At[(KO) & 1] + row * 256 + sc * 16); \
                }                                                                 \
                _Pragma("unroll")                                                 \
                for (int ks = 0; ks < 4; ++ks) {                                  \
                    acc[m][0] = __builtin_amdgcn_mfma_f32_16x16x32_bf16(a[ks], BA[ks], acc[m][0], 0, 0, 0); \
                    acc[m][1] = __builtin_amdgcn_mfma_f32_16x16x32_bf16(a[ks], BB[ks], acc[m][1], 0, 0, 0); \
                }                                                                 \
            }                                                                     \
            __builtin_amdgcn_s_setprio(0);                                        \
        }

    CONV_ITER(0, b0a, b0b, LOADB1, 8)
    CONV_ITER(1, b1a, b1b, LOADB0, 8)
    CONV_ITER(2, b0a, b0b, LOADB1, 8)
    CONV_ITER(3, b1a, b1b, LOADB0, 8)
    CONV_ITER(4, b0a, b0b, LOADB1, 8)
    CONV_ITER(5, b1a, b1b, LOADB0, 8)
    CONV_ITER(6, b0a, b0b, LOADB1, 8)
    CONV_ITER(7, b1a, b1b, LOADB0, 8)
    CONV_ITER(8, b0a, b0b, LOADB1, 0)
    #undef CONV_ITER
    #undef STAGE
    #undef LOADB0
    #undef LOADB1

    // ---- per-channel stats (each wave owns channels [wv*32, wv*32+32)) ----
    #pragma unroll
    for (int j = 0; j < 2; ++j) {
        float s = 0.f, q = 0.f;
        #pragma unroll
        for (int m = 0; m < 4; ++m)
            #pragma unroll
            for (int r = 0; r < 4; ++r) { float v = acc[m][j][r]; s += v; q += v * v; }
        s += __shfl_xor(s, 16); s += __shfl_xor(s, 32);
        q += __shfl_xor(q, 16); q += __shfl_xor(q, 32);
        if (lane < 16) {
            atomicAdd(&statS[wv * 32 + j * 16 + lane], s);
            atomicAdd(&statQ[wv * 32 + j * 16 + lane], q);
        }
    }

    // ---- write raw conv output (bf16, plain coalesced stores) ----
    #pragma unroll
    for (int m = 0; m < 4; ++m)
        #pragma unroll
        for (int j = 0; j < 2; ++j) {
            int col = (wv * 2 + j) * 16 + l15;
            #pragma unroll
            for (int r = 0; r < 4; ++r) {
                int row = tile + m * 16 + asub * 4 + r;
                Yraw[(size_t)row * C_CH + col] = f2b(acc[m][j][r]);
            }
        }
}

// ---------------- BN finalize / apply ----------------

__global__ void finalize_bn_k(const float* __restrict__ S, const float* __restrict__ Q,
                              const float* __restrict__ gamma, const float* __restrict__ beta,
                              float* __restrict__ scale, float* __restrict__ bias, float invN) {
    int c = threadIdx.x;
    if (c < C_CH) {
        float mu = S[c] * invN;
        float var = Q[c] * invN - mu * mu;
        float inv = rsqrtf(var + 1e-4f);
        float sc = gamma[c] * inv;
        scale[c] = sc;
        bias[c] = beta[c] - mu * sc;
    }
}

__global__ void bn_relu_k(unsigned short* __restrict__ y,
                          const float* __restrict__ scale, const float* __restrict__ bias, int n8) {
    int i0 = blockIdx.x * blockDim.x + threadIdx.x;
    int S = gridDim.x * blockDim.x;
    int c0 = (i0 * 8) & (C_CH - 1);
    float sc[8], bs[8];
    #pragma unroll
    for (int j = 0; j < 8; ++j) { sc[j] = scale[c0 + j]; bs[j] = bias[c0 + j]; }
    for (int i = i0; i < n8; i += S) {
        u16x8 v = ((const u16x8*)y)[i];
        #pragma unroll
        for (int j = 0; j < 8; ++j) {
            float x = b2f((unsigned short)v[j]);
            x = fmaxf(x * sc[j] + bs[j], 0.f);
            v[j] = (unsigned short)f2b(x);
        }
        ((u16x8*)y)[i] = v;   // stays L3-hot for conv2's gather
    }
}

// BF16RES: residual from bf16 featb (saves 102MB) when ws had room for out2raw.
template <bool BF16RES>
__global__ void final_fuse_k(const unsigned short* __restrict__ raw,
                             const float* __restrict__ featf,
                             const unsigned short* __restrict__ featb,
                             const float* __restrict__ scale, const float* __restrict__ bias,
                             float* __restrict__ out, int n4) {
    int i0 = blockIdx.x * blockDim.x + threadIdx.x;
    int S = gridDim.x * blockDim.x;
    int c0 = (i0 * 4) & (C_CH - 1);
    float sc[4], bs[4];
    #pragma unroll
    for (int j = 0; j < 4; ++j) { sc[j] = scale[c0 + j]; bs[j] = bias[c0 + j]; }
    for (int i = i0; i < n4; i += S) {
        u16x4 r = __builtin_nontemporal_load((const u16x4*)raw + i);
        float fx, fy, fz, fw;
        if (BF16RES) {
            u16x4 f = __builtin_nontemporal_load((const u16x4*)featb + i);
            fx = b2f(f[0]); fy = b2f(f[1]); fz = b2f(f[2]); fw = b2f(f[3]);
        } else {
            f32x4 f = __builtin_nontemporal_load((const f32x4*)featf + i);
            fx = f[0]; fy = f[1]; fz = f[2]; fw = f[3];
        }
        f32x4 o;
        o[0] = fmaxf(b2f(r[0]) * sc[0] + bs[0] + fx, 0.f);
        o[1] = fmaxf(b2f(r[1]) * sc[1] + bs[1] + fy, 0.f);
        o[2] = fmaxf(b2f(r[2]) * sc[2] + bs[2] + fz, 0.f);
        o[3] = fmaxf(b2f(r[3]) * sc[3] + bs[3] + fw, 0.f);
        __builtin_nontemporal_store(o, (f32x4*)out + i);
    }
}

// ---------------- launch ----------------

extern "C" void kernel_launch(void* const* d_in, const int* in_sizes, int n_in,
                              void* d_out, int out_size, void* d_ws, size_t ws_size,
                              hipStream_t stream) {
    const float* feat = (const float*)d_in[0];
    const float* W1 = (const float*)d_in[1];
    const float* W2 = (const float*)d_in[2];
    const float* g1 = (const float*)d_in[3];
    const float* b1 = (const float*)d_in[4];
    const float* g2 = (const float*)d_in[5];
    const float* b2 = (const float*)d_in[6];
    const int* nidx = (const int*)d_in[7];
    const void* nmask = d_in[8];

    const int N = in_sizes[0] / C_CH;   // 400000

    char* ws = (char*)d_ws;
    unsigned short* featb = (unsigned short*)ws;                          // (N+1) x 128 bf16
    size_t off = (size_t)(N + 1) * C_CH * 2;
    off = (off + 255) & ~(size_t)255;
    unsigned short* Wp1 = (unsigned short*)(ws + off); off += (size_t)K_OFF * C_CH * C_CH * 2;
    unsigned short* Wp2 = (unsigned short*)(ws + off); off += (size_t)K_OFF * C_CH * C_CH * 2;
    float* stats = (float*)(ws + off);
    float* S1 = stats;        float* Q1 = stats + 128;
    float* S2 = stats + 256;  float* Q2 = stats + 384;
    float* sc1 = stats + 512; float* bi1 = stats + 640;
    float* sc2 = stats + 768; float* bi2 = stats + 896;
    int* flagA = ((int*)stats) + 1024;
    int* flagB = ((int*)stats) + 1025;
    size_t off2 = off + 8192;   // end of stats region, aligned

    // conv2 output: separate ws region if it fits (keeps featb alive for bf16
    // residual); else overwrite featb (f32-feat residual fallback).
    size_t rawBytes = (size_t)N * C_CH * 2;
    bool sepOut = (ws_size >= off2 + rawBytes);
    unsigned short* out2raw = sepOut ? (unsigned short*)(ws + off2) : featb;

    // scratch inside d_out: y1 = rows [0, N] bf16 (~102.4MB); rewritten by final_fuse.
    unsigned short* y1 = (unsigned short*)d_out;

    hipLaunchKernelGGL(prep_k, dim3(2048), dim3(256), 0, stream,
                       feat, featb, N * C_CH / 4,
                       W1, Wp1, W2, Wp2,
                       stats, (unsigned int*)(featb + (size_t)N * C_CH),
                       (unsigned int*)(y1 + (size_t)N * C_CH),
                       (const unsigned char*)nmask, flagA, flagB);

    hipLaunchKernelGGL(conv_kernel, dim3(N / MTILE), dim3(256), 0, stream,
                       featb, Wp1, nidx, nmask, flagA, flagB, N, y1, S1, Q1);
    hipLaunchKernelGGL(finalize_bn_k, dim3(1), dim3(128), 0, stream, S1, Q1, g1, b1, sc1, bi1, 1.0f / N);
    hipLaunchKernelGGL(bn_relu_k, dim3(2048), dim3(256), 0, stream, y1, sc1, bi1, N * C_CH / 8);

    hipLaunchKernelGGL(conv_kernel, dim3(N / MTILE), dim3(256), 0, stream,
                       y1, Wp2, nidx, nmask, flagA, flagB, N, out2raw, S2, Q2);
    hipLaunchKernelGGL(finalize_bn_k, dim3(1), dim3(128), 0, stream, S2, Q2, g2, b2, sc2, bi2, 1.0f / N);
    if (sepOut) {
        hipLaunchKernelGGL(final_fuse_k<true>, dim3(2048), dim3(256), 0, stream,
                           out2raw, feat, featb, sc2, bi2, (float*)d_out, N * C_CH / 4);
    } else {
        hipLaunchKernelGGL(final_fuse_k<false>, dim3(2048), dim3(256), 0, stream,
                           out2raw, feat, featb, sc2, bi2, (float*)d_out, N * C_CH / 4);
    }
}

// Round 16
// 518.292 us; speedup vs baseline: 1.6807x; 1.0112x over previous
//
#include <hip/hip_runtime.h>

// SparseBasicBlock: conv1(gather-GEMM) -> BN+ReLU -> conv2 -> BN -> +residual -> ReLU
// bf16 MFMA 16x16x32, fp32 accum. Conv: MTILE=64, 4 waves (col-split), 2 x 16KB
// LDS gather double-buffer (1-deep) via global_load_lds + register-double-
// buffered B, exact counted vmcnt(8) + one raw s_barrier per ko.
// R16: finalize_bn folded into bn_relu/final_fuse (per-block scale/bias
// computation, 2 launches removed). Conv core unchanged (R12/R15 plateau).

#define C_CH 128
#define K_OFF 9
#define MTILE 64

typedef __attribute__((ext_vector_type(8))) short bf16x8;
typedef __attribute__((ext_vector_type(4))) float f32x4;
typedef __attribute__((ext_vector_type(4))) unsigned short u16x4;
typedef __attribute__((ext_vector_type(8))) unsigned short u16x8;

typedef __attribute__((address_space(1))) const unsigned int* gas_p;
typedef __attribute__((address_space(3))) unsigned int* las_p;

__device__ __forceinline__ void gload_lds16(const unsigned short* g, unsigned short* l) {
    __builtin_amdgcn_global_load_lds((gas_p)g, (las_p)l, 16, 0, 0);
}

__device__ __forceinline__ unsigned short f2b(float f) {
    union { float f; unsigned u; } v; v.f = f;
    unsigned r = v.u + 0x7fffu + ((v.u >> 16) & 1u);   // round-to-nearest-even
    return (unsigned short)(r >> 16);
}
__device__ __forceinline__ float b2f(unsigned short h) {
    union { unsigned u; float f; } v; v.u = ((unsigned)h) << 16;
    return v.f;
}

// ---------------- prep (merged init + detect + convert + pack) ----------------
// block 0: zero stats/flags + two zero-sentinel rows
// blocks 1..64: detect mask dtype from first 16KB
// all blocks: grid-stride {feat->bf16 convert | W1,W2 pack}
// Wp[((ko*8+nt)*4+ks)*512 + lane*8 + j] = W[ko][ks*32+(lane>>4)*8+j][nt*16+(lane&15)]
__global__ void prep_k(const float* __restrict__ x, unsigned short* __restrict__ y, int n4,
                       const float* __restrict__ W1, unsigned short* __restrict__ Wp1,
                       const float* __restrict__ W2, unsigned short* __restrict__ Wp2,
                       float* stats, unsigned int* zrow1, unsigned int* zrow2,
                       const unsigned char* __restrict__ m, int* flagA, int* flagB) {
    const int t = threadIdx.x;
    if (blockIdx.x == 0) {
        if (t < 256) { stats[t] = 0.f; stats[256 + t] = 0.f; }
        if (t >= 256 && t < 258) ((int*)stats)[1024 + (t - 256)] = 0;  // flagA, flagB
        if (t < 64) { zrow1[t] = 0u; zrow2[t] = 0u; }
    } else if (blockIdx.x <= 64) {
        int i = (blockIdx.x - 1) * 256 + t;   // first 16KB of mask
        unsigned char v = m[i];
        if ((i & 3) != 0 && v != 0) atomicOr(flagA, 1);
        if (v > 1) atomicOr(flagB, 1);
    }
    const int PACK = K_OFF * 8 * 4 * 512;      // per-tensor packed elements
    int i = blockIdx.x * blockDim.x + t;
    int s = gridDim.x * blockDim.x;
    int tot = n4 + 2 * PACK;
    for (; i < tot; i += s) {
        if (i < n4) {
            f32x4 f = __builtin_nontemporal_load((const f32x4*)x + i);
            u16x4 o;
            o[0] = f2b(f[0]); o[1] = f2b(f[1]); o[2] = f2b(f[2]); o[3] = f2b(f[3]);
            ((u16x4*)y)[i] = o;              // normal store: featb should be L3-hot
        } else {
            int ii = i - n4;
            const float* W = (ii < PACK) ? W1 : W2;
            unsigned short* Wp = (ii < PACK) ? Wp1 : Wp2;
            if (ii >= PACK) ii -= PACK;
            int j = ii & 7;
            int l = (ii >> 3) & 63;
            int frag = ii >> 9;
            int ks = frag & 3;
            int nt = (frag >> 2) & 7;
            int ko = frag >> 5;
            int cin = ks * 32 + (l >> 4) * 8 + j;
            int cout = nt * 16 + (l & 15);
            Wp[ii] = f2b(W[ko * C_CH * C_CH + cin * C_CH + cout]);
        }
    }
}

// ---------------- gather-GEMM conv ----------------

__global__ __launch_bounds__(256, 3) void conv_kernel(
    const unsigned short* __restrict__ Xb,   // (N+1) x 128 bf16 (row N = zeros)
    const unsigned short* __restrict__ Wp,   // packed weights (fragment layout)
    const int* __restrict__ nidx,            // N x 9 rulebook indices
    const void* __restrict__ nmask,          // N x 9 mask (dtype per flags)
    const int* __restrict__ flagA, const int* __restrict__ flagB,
    int Nzero,                               // zero-sentinel row index (= N)
    unsigned short* __restrict__ Yraw,       // N x 128 bf16 raw conv output
    float* __restrict__ statS, float* __restrict__ statQ)
{
    const int tid = threadIdx.x;
    const int lane = tid & 63;
    const int wv = tid >> 6;          // wave 0..3 owns cols [wv*32, wv*32+32)
    const int tile = blockIdx.x * MTILE;
    const int asub = lane >> 4;       // 0..3
    const int l15 = lane & 15;

    __shared__ alignas(16) unsigned short At[2][MTILE * C_CH]; // 2 x 16KB, linear
    __shared__ int sIdxT[K_OFF][MTILE];                        // 2.25KB

    // fold mask + idx inline; rulebook via nt-loads (read-once, keep L3 clean)
    {
        int fa = *flagA, fb = *flagB;
        for (int i = tid; i < MTILE * K_OFF; i += 256) {
            int r = i / K_OFF, k = i - r * K_OFF;
            size_t gi = (size_t)(tile + r) * K_OFF + k;
            bool t;
            if (!fa)       t = __builtin_nontemporal_load((const int*)nmask + gi) != 0;
            else if (fb)   t = __builtin_nontemporal_load((const unsigned*)nmask + gi) != 0;
            else           t = __builtin_nontemporal_load((const unsigned char*)nmask + gi) != 0;
            sIdxT[k][r] = t ? __builtin_nontemporal_load(nidx + gi) : Nzero;
        }
    }
    __syncthreads();

    const int r_st = tid >> 4;      // 0..15
    const int ch_st = tid & 15;     // 0..15

    #define STAGE(buf, ko)                                                        \
        {                                                                         \
            _Pragma("unroll")                                                     \
            for (int jr = 0; jr < 4; ++jr) {                                      \
                int r = jr * 16 + r_st;                                           \
                int g = sIdxT[ko][r];                                             \
                const unsigned short* src =                                       \
                    Xb + (size_t)g * C_CH + ((ch_st ^ (r & 7)) * 8);              \
                unsigned short* dst = &At[buf][r * C_CH + ch_st * 8];             \
                gload_lds16(src, dst);                                            \
            }                                                                     \
        }

    #define LOADB0(ko)                                                            \
        {                                                                         \
            const unsigned short* wb = Wp + (size_t)(ko) * (8 * 4 * 512) + lane * 8; \
            _Pragma("unroll")                                                     \
            for (int ks = 0; ks < 4; ++ks) {                                      \
                b0a[ks] = *(const bf16x8*)(wb + ((wv * 2 + 0) * 4 + ks) * 512);   \
                b0b[ks] = *(const bf16x8*)(wb + ((wv * 2 + 1) * 4 + ks) * 512);   \
            }                                                                     \
        }
    #define LOADB1(ko)                                                            \
        {                                                                         \
            const unsigned short* wb = Wp + (size_t)(ko) * (8 * 4 * 512) + lane * 8; \
            _Pragma("unroll")                                                     \
            for (int ks = 0; ks < 4; ++ks) {                                      \
                b1a[ks] = *(const bf16x8*)(wb + ((wv * 2 + 0) * 4 + ks) * 512);   \
                b1b[ks] = *(const bf16x8*)(wb + ((wv * 2 + 1) * 4 + ks) * 512);   \
            }                                                                     \
        }

    f32x4 acc[4][2];
    #pragma unroll
    for (int m = 0; m < 4; ++m) { acc[m][0] = (f32x4){0,0,0,0}; acc[m][1] = (f32x4){0,0,0,0}; }

    bf16x8 b0a[4], b0b[4], b1a[4], b1b[4];

    // prologue queue: s0(4) B0(8)
    STAGE(0, 0);
    LOADB0(0);

    // Queue at the wait: B(KO)8 s(KO)4 | B(KO+1)8 -> vmcnt(8) exact.
    // Guarded STAGE/LOADB indices clamped with % K_OFF (dead at KO=8).
    #define CONV_ITER(KO, BA, BB, LB, VM)                                         \
        {                                                                         \
            if ((KO) + 1 < K_OFF) { LB((((KO) + 1) % K_OFF)); }                   \
            __builtin_amdgcn_sched_barrier(0);                                    \
            asm volatile("s_waitcnt vmcnt(" #VM ")" ::: "memory");                \
            __builtin_amdgcn_s_barrier();                                         \
            __builtin_amdgcn_sched_barrier(0);                                    \
            if ((KO) + 1 < K_OFF) { STAGE((((KO) + 1) & 1), (((KO) + 1) % K_OFF)); } \
            __builtin_amdgcn_s_setprio(1);                                        \
            _Pragma("unroll")                                                     \
            for (int m = 0; m < 4; ++m) {                                         \
                bf16x8 a[4];                                                      \
                _Pragma("unroll")                                                 \
                for (int ks = 0; ks < 4; ++ks) {                                  \
                    int row = m * 16 + l15;                                       \
                    int sc = (ks * 4 + asub) ^ (row & 7);                         \
                    a[ks] = *(const bf16x8*)((const char*)At[(KO) & 1] + row * 256 + sc * 16); \
                }                                                                 \
                _Pragma("unroll")                                                 \
                for (int ks = 0; ks < 4; ++ks) {                                  \
                    acc[m][0] = __builtin_amdgcn_mfma_f32_16x16x32_bf16(a[ks], BA[ks], acc[m][0], 0, 0, 0); \
                    acc[m][1] = __builtin_amdgcn_mfma_f32_16x16x32_bf16(a[ks], BB[ks], acc[m][1], 0, 0, 0); \
                }                                                                 \
            }                                                                     \
            __builtin_amdgcn_s_setprio(0);                                        \
        }

    CONV_ITER(0, b0a, b0b, LOADB1, 8)
    CONV_ITER(1, b1a, b1b, LOADB0, 8)
    CONV_ITER(2, b0a, b0b, LOADB1, 8)
    CONV_ITER(3, b1a, b1b, LOADB0, 8)
    CONV_ITER(4, b0a, b0b, LOADB1, 8)
    CONV_ITER(5, b1a, b1b, LOADB0, 8)
    CONV_ITER(6, b0a, b0b, LOADB1, 8)
    CONV_ITER(7, b1a, b1b, LOADB0, 8)
    CONV_ITER(8, b0a, b0b, LOADB1, 0)
    #undef CONV_ITER
    #undef STAGE
    #undef LOADB0
    #undef LOADB1

    // ---- per-channel stats (each wave owns channels [wv*32, wv*32+32)) ----
    #pragma unroll
    for (int j = 0; j < 2; ++j) {
        float s = 0.f, q = 0.f;
        #pragma unroll
        for (int m = 0; m < 4; ++m)
            #pragma unroll
            for (int r = 0; r < 4; ++r) { float v = acc[m][j][r]; s += v; q += v * v; }
        s += __shfl_xor(s, 16); s += __shfl_xor(s, 32);
        q += __shfl_xor(q, 16); q += __shfl_xor(q, 32);
        if (lane < 16) {
            atomicAdd(&statS[wv * 32 + j * 16 + lane], s);
            atomicAdd(&statQ[wv * 32 + j * 16 + lane], q);
        }
    }

    // ---- write raw conv output (bf16, plain coalesced stores) ----
    #pragma unroll
    for (int m = 0; m < 4; ++m)
        #pragma unroll
        for (int j = 0; j < 2; ++j) {
            int col = (wv * 2 + j) * 16 + l15;
            #pragma unroll
            for (int r = 0; r < 4; ++r) {
                int row = tile + m * 16 + asub * 4 + r;
                Yraw[(size_t)row * C_CH + col] = f2b(acc[m][j][r]);
            }
        }
}

// ---------------- BN apply (scale/bias computed per-block from S/Q) ----------------

__global__ void bn_relu_k(unsigned short* __restrict__ y,
                          const float* __restrict__ S, const float* __restrict__ Q,
                          const float* __restrict__ gamma, const float* __restrict__ beta,
                          float invN, int n8) {
    __shared__ float sSc[C_CH], sBs[C_CH];
    int t = threadIdx.x;
    if (t < C_CH) {
        float mu = S[t] * invN;
        float var = Q[t] * invN - mu * mu;
        float inv = rsqrtf(var + 1e-4f);
        float sc = gamma[t] * inv;
        sSc[t] = sc;
        sBs[t] = beta[t] - mu * sc;
    }
    __syncthreads();

    int i0 = blockIdx.x * blockDim.x + t;
    int St = gridDim.x * blockDim.x;        // St*8 % 128 == 0 -> c0 invariant
    int c0 = (i0 * 8) & (C_CH - 1);
    float sc[8], bs[8];
    #pragma unroll
    for (int j = 0; j < 8; ++j) { sc[j] = sSc[c0 + j]; bs[j] = sBs[c0 + j]; }
    for (int i = i0; i < n8; i += St) {
        u16x8 v = ((const u16x8*)y)[i];
        #pragma unroll
        for (int j = 0; j < 8; ++j) {
            float x = b2f((unsigned short)v[j]);
            x = fmaxf(x * sc[j] + bs[j], 0.f);
            v[j] = (unsigned short)f2b(x);
        }
        ((u16x8*)y)[i] = v;   // stays L3-hot for conv2's gather
    }
}

// BF16RES: residual from bf16 featb (saves 102MB) when ws had room for out2raw.
template <bool BF16RES>
__global__ void final_fuse_k(const unsigned short* __restrict__ raw,
                             const float* __restrict__ featf,
                             const unsigned short* __restrict__ featb,
                             const float* __restrict__ S, const float* __restrict__ Q,
                             const float* __restrict__ gamma, const float* __restrict__ beta,
                             float invN, float* __restrict__ out, int n4) {
    __shared__ float sSc[C_CH], sBs[C_CH];
    int t = threadIdx.x;
    if (t < C_CH) {
        float mu = S[t] * invN;
        float var = Q[t] * invN - mu * mu;
        float inv = rsqrtf(var + 1e-4f);
        float sc = gamma[t] * inv;
        sSc[t] = sc;
        sBs[t] = beta[t] - mu * sc;
    }
    __syncthreads();

    int i0 = blockIdx.x * blockDim.x + t;
    int St = gridDim.x * blockDim.x;        // St*4 % 128 == 0 -> c0 invariant
    int c0 = (i0 * 4) & (C_CH - 1);
    float sc[4], bs[4];
    #pragma unroll
    for (int j = 0; j < 4; ++j) { sc[j] = sSc[c0 + j]; bs[j] = sBs[c0 + j]; }
    for (int i = i0; i < n4; i += St) {
        u16x4 r = __builtin_nontemporal_load((const u16x4*)raw + i);
        float fx, fy, fz, fw;
        if (BF16RES) {
            u16x4 f = __builtin_nontemporal_load((const u16x4*)featb + i);
            fx = b2f(f[0]); fy = b2f(f[1]); fz = b2f(f[2]); fw = b2f(f[3]);
        } else {
            f32x4 f = __builtin_nontemporal_load((const f32x4*)featf + i);
            fx = f[0]; fy = f[1]; fz = f[2]; fw = f[3];
        }
        f32x4 o;
        o[0] = fmaxf(b2f(r[0]) * sc[0] + bs[0] + fx, 0.f);
        o[1] = fmaxf(b2f(r[1]) * sc[1] + bs[1] + fy, 0.f);
        o[2] = fmaxf(b2f(r[2]) * sc[2] + bs[2] + fz, 0.f);
        o[3] = fmaxf(b2f(r[3]) * sc[3] + bs[3] + fw, 0.f);
        __builtin_nontemporal_store(o, (f32x4*)out + i);
    }
}

// ---------------- launch ----------------

extern "C" void kernel_launch(void* const* d_in, const int* in_sizes, int n_in,
                              void* d_out, int out_size, void* d_ws, size_t ws_size,
                              hipStream_t stream) {
    const float* feat = (const float*)d_in[0];
    const float* W1 = (const float*)d_in[1];
    const float* W2 = (const float*)d_in[2];
    const float* g1 = (const float*)d_in[3];
    const float* b1 = (const float*)d_in[4];
    const float* g2 = (const float*)d_in[5];
    const float* b2 = (const float*)d_in[6];
    const int* nidx = (const int*)d_in[7];
    const void* nmask = d_in[8];

    const int N = in_sizes[0] / C_CH;   // 400000

    char* ws = (char*)d_ws;
    unsigned short* featb = (unsigned short*)ws;                          // (N+1) x 128 bf16
    size_t off = (size_t)(N + 1) * C_CH * 2;
    off = (off + 255) & ~(size_t)255;
    unsigned short* Wp1 = (unsigned short*)(ws + off); off += (size_t)K_OFF * C_CH * C_CH * 2;
    unsigned short* Wp2 = (unsigned short*)(ws + off); off += (size_t)K_OFF * C_CH * C_CH * 2;
    float* stats = (float*)(ws + off);
    float* S1 = stats;        float* Q1 = stats + 128;
    float* S2 = stats + 256;  float* Q2 = stats + 384;
    int* flagA = ((int*)stats) + 1024;
    int* flagB = ((int*)stats) + 1025;
    size_t off2 = off + 8192;   // end of stats region, aligned

    // conv2 output: separate ws region if it fits (keeps featb alive for bf16
    // residual); else overwrite featb (f32-feat residual fallback).
    size_t rawBytes = (size_t)N * C_CH * 2;
    bool sepOut = (ws_size >= off2 + rawBytes);
    unsigned short* out2raw = sepOut ? (unsigned short*)(ws + off2) : featb;

    // scratch inside d_out: y1 = rows [0, N] bf16 (~102.4MB); rewritten by final_fuse.
    unsigned short* y1 = (unsigned short*)d_out;

    hipLaunchKernelGGL(prep_k, dim3(2048), dim3(256), 0, stream,
                       feat, featb, N * C_CH / 4,
                       W1, Wp1, W2, Wp2,
                       stats, (unsigned int*)(featb + (size_t)N * C_CH),
                       (unsigned int*)(y1 + (size_t)N * C_CH),
                       (const unsigned char*)nmask, flagA, flagB);

    hipLaunchKernelGGL(conv_kernel, dim3(N / MTILE), dim3(256), 0, stream,
                       featb, Wp1, nidx, nmask, flagA, flagB, N, y1, S1, Q1);
    hipLaunchKernelGGL(bn_relu_k, dim3(2048), dim3(256), 0, stream,
                       y1, S1, Q1, g1, b1, 1.0f / N, N * C_CH / 8);

    hipLaunchKernelGGL(conv_kernel, dim3(N / MTILE), dim3(256), 0, stream,
                       y1, Wp2, nidx, nmask, flagA, flagB, N, out2raw, S2, Q2);
    if (sepOut) {
        hipLaunchKernelGGL(final_fuse_k<true>, dim3(2048), dim3(256), 0, stream,
                           out2raw, feat, featb, S2, Q2, g2, b2, 1.0f / N,
                           (float*)d_out, N * C_CH / 4);
    } else {
        hipLaunchKernelGGL(final_fuse_k<false>, dim3(2048), dim3(256), 0, stream,
                           out2raw, feat, featb, S2, Q2, g2, b2, 1.0f / N,
                           (float*)d_out, N * C_CH / 4);
    }
}